// Round 7
// baseline (248.503 us; speedup 1.0000x reference)
//
#include <hip/hip_runtime.h>

#define NB 16
#define NN 2048
#define DH 64
#define NSEL 228     // int(30 * ln(2048))
#define KS 8         // attention key-split chunks
#define CHUNK (NN / KS)
#define RS 4         // rowstat key-split
#define EPSBAND 2.0e-3f  // >> worst-case bf16x3 score error (~7e-4)
#define MAXB 32      // recheck blocks per batch (loops if nband > MAXB)

using s16x8 = __attribute__((ext_vector_type(8))) short;
using f32x16 = __attribute__((ext_vector_type(16))) float;

static __device__ __forceinline__ unsigned short f2bf(float x) {
  unsigned int u = __float_as_uint(x);
  u += 0x7fffu + ((u >> 16) & 1u);  // RNE; fine for finite data
  return (unsigned short)(u >> 16);
}
static __device__ __forceinline__ float bf2f(unsigned short h) {
  return __uint_as_float(((unsigned int)h) << 16);
}
static __device__ __forceinline__ unsigned int enc(float f) {
  unsigned int u = __float_as_uint(f);
  return (u & 0x80000000u) ? ~u : (u | 0x80000000u);
}
static __device__ __forceinline__ float dec(unsigned int k) {
  return (k & 0x80000000u) ? __uint_as_float(k & 0x7fffffffu)
                           : __uint_as_float(~k);
}

// ---------------------------------------------------------------------------
// K -> bf16 hi/lo split (done once; rowstat re-reads it 4x via L3)
// ---------------------------------------------------------------------------
__global__ __launch_bounds__(256) void convk_kernel(const float* __restrict__ K,
                                                    unsigned short* __restrict__ Khi,
                                                    unsigned short* __restrict__ Klo) {
  const size_t e = ((size_t)blockIdx.x * 256 + threadIdx.x) * 8;
  float4 a = *(const float4*)(K + e);
  float4 b = *(const float4*)(K + e + 4);
  float v[8] = {a.x, a.y, a.z, a.w, b.x, b.y, b.z, b.w};
  union { unsigned short u[8]; s16x8 s; } H, L;
  #pragma unroll
  for (int j = 0; j < 8; ++j) {
    unsigned short h = f2bf(v[j]);
    H.u[j] = h;
    L.u[j] = f2bf(v[j] - bf2f(h));
  }
  *(s16x8*)(Khi + e) = H.s;
  *(s16x8*)(Klo + e) = L.s;
}

// ---------------------------------------------------------------------------
// Partial column sums of K (for the EXACT mean term: mean_i = q_i . Ksum / N)
// ---------------------------------------------------------------------------
__global__ __launch_bounds__(256) void kcolsum_kernel(const float* __restrict__ K,
                                                      float* __restrict__ Kpart) {
  __shared__ float part[4][64];
  const int b = blockIdx.y, ch = blockIdx.x;
  const int d = threadIdx.x & 63, g = threadIdx.x >> 6;
  const float* Kb = K + ((size_t)b * NN + ch * 128) * DH;
  float s = 0.f;
  for (int r = g; r < 128; r += 4) s += Kb[r * DH + d];
  part[g][d] = s;
  __syncthreads();
  if (threadIdx.x < 64)
    Kpart[((size_t)b * 16 + ch) * 64 + threadIdx.x] =
        part[0][threadIdx.x] + part[1][threadIdx.x] +
        part[2][threadIdx.x] + part[3][threadIdx.x];
}

// ---------------------------------------------------------------------------
// Kernel A (MFMA): rowmax of S = Q K^T over a 512-key chunk, bf16x3 split.
// (unchanged from round 6 -- proven)
// ---------------------------------------------------------------------------
__global__ __launch_bounds__(256, 4) void rowstat_mfma(const float* __restrict__ Q,
                                                       const unsigned short* __restrict__ Khi,
                                                       const unsigned short* __restrict__ Klo,
                                                       float* __restrict__ Mmax) {
  __shared__ __align__(16) unsigned short KHs[128 * 64];
  __shared__ __align__(16) unsigned short KLs[128 * 64];
  const int b = blockIdx.y, cz = blockIdx.z;
  const int qbase = blockIdx.x * 128;
  const int tid = threadIdx.x;
  const int w = tid >> 6, lane = tid & 63;
  const int l31 = lane & 31, hi5 = lane >> 5;

  s16x8 qh[4], ql[4];
  {
    const float* qrow = Q + ((size_t)b * NN + qbase + w * 32 + l31) * DH;
    #pragma unroll
    for (int ks = 0; ks < 4; ++ks) {
      const int d0 = ks * 16 + hi5 * 8;
      float4 x = *(const float4*)(qrow + d0);
      float4 y = *(const float4*)(qrow + d0 + 4);
      float v[8] = {x.x, x.y, x.z, x.w, y.x, y.y, y.z, y.w};
      union { unsigned short u[8]; s16x8 s; } H, L;
      #pragma unroll
      for (int j = 0; j < 8; ++j) {
        unsigned short h = f2bf(v[j]);
        H.u[j] = h;
        L.u[j] = f2bf(v[j] - bf2f(h));
      }
      qh[ks] = H.s;
      ql[ks] = L.s;
    }
  }

  const size_t kbase = ((size_t)b * NN + cz * (NN / RS)) * DH;
  f32x16 vmax;
  #pragma unroll
  for (int i = 0; i < 16; ++i) vmax[i] = -3.0e38f;

  const int sr = tid >> 1;
  const int sh = tid & 1;

  for (int stage = 0; stage < NN / RS / 128; ++stage) {
    __syncthreads();
    {
      const size_t g = kbase + (size_t)(stage * 128 + sr) * DH + sh * 32;
      const unsigned short* gh = Khi + g;
      const unsigned short* gl = Klo + g;
      #pragma unroll
      for (int c = 0; c < 4; ++c) {
        s16x8 hv = *(const s16x8*)(gh + c * 8);
        s16x8 lv = *(const s16x8*)(gl + c * 8);
        const int chn = (sh * 4 + c) ^ (sr & 7);
        *(s16x8*)&KHs[(sr * 8 + chn) * 8] = hv;
        *(s16x8*)&KLs[(sr * 8 + chn) * 8] = lv;
      }
    }
    __syncthreads();

    #pragma unroll
    for (int ksub = 0; ksub < 4; ++ksub) {
      const int kr = ksub * 32 + l31;
      f32x16 acc;
      #pragma unroll
      for (int i = 0; i < 16; ++i) acc[i] = 0.f;
      #pragma unroll
      for (int ks = 0; ks < 4; ++ks) {
        const int chn = (ks * 2 + hi5) ^ (kr & 7);
        s16x8 ah = *(const s16x8*)&KHs[(kr * 8 + chn) * 8];
        s16x8 al = *(const s16x8*)&KLs[(kr * 8 + chn) * 8];
        acc = __builtin_amdgcn_mfma_f32_32x32x16_bf16(ah, qh[ks], acc, 0, 0, 0);
        acc = __builtin_amdgcn_mfma_f32_32x32x16_bf16(al, qh[ks], acc, 0, 0, 0);
        acc = __builtin_amdgcn_mfma_f32_32x32x16_bf16(ah, ql[ks], acc, 0, 0, 0);
      }
      #pragma unroll
      for (int i = 0; i < 16; ++i) vmax[i] = fmaxf(vmax[i], acc[i]);
    }
  }

  float m = vmax[0];
  #pragma unroll
  for (int i = 1; i < 16; ++i) m = fmaxf(m, vmax[i]);
  m = fmaxf(m, __shfl_xor(m, 32));
  if (lane < 32)
    Mmax[((size_t)cz * NB + b) * NN + qbase + w * 32 + lane] = m;
}

// ---------------------------------------------------------------------------
// B0: keys + mean for all rows, PARALLEL (128 blocks; round-6 select did this
// with 16 blocks -> 75 us of unhidden latency).
// ---------------------------------------------------------------------------
__global__ __launch_bounds__(256) void mstat_kernel(const float* __restrict__ Q,
                                                    const float* __restrict__ Mmax,
                                                    const float* __restrict__ Kpart,
                                                    unsigned int* __restrict__ keysW,
                                                    float* __restrict__ meanv) {
  __shared__ float Ksl[64];
  const int b = blockIdx.y;
  const int seg = blockIdx.x;
  const int tid = threadIdx.x;
  if (tid < 64) {
    float s = 0.f;
    #pragma unroll
    for (int c = 0; c < 16; ++c) s += Kpart[((size_t)b * 16 + c) * 64 + tid];
    Ksl[tid] = s;
  }
  __syncthreads();
  const int i = seg * 256 + tid;
  float mv = -3.0e38f;
  #pragma unroll
  for (int cz = 0; cz < RS; ++cz)
    mv = fmaxf(mv, Mmax[((size_t)cz * NB + b) * NN + i]);
  const float* qrow = Q + ((size_t)b * NN + i) * DH;
  float s = 0.f;
  #pragma unroll
  for (int d4 = 0; d4 < 16; ++d4) {
    float4 qv = *(const float4*)(qrow + d4 * 4);
    s = fmaf(qv.x, Ksl[d4 * 4 + 0], s);
    s = fmaf(qv.y, Ksl[d4 * 4 + 1], s);
    s = fmaf(qv.z, Ksl[d4 * 4 + 2], s);
    s = fmaf(qv.w, Ksl[d4 * 4 + 3], s);
  }
  const float mean = s * (1.0f / NN);
  meanv[(size_t)b * NN + i] = mean;
  keysW[(size_t)b * NN + i] = enc(mv - mean);
}

// ---------------------------------------------------------------------------
// shared radix helper: largest v with count(keys >= v) >= NSEL
// ---------------------------------------------------------------------------
static __device__ unsigned int radix_thresh(const unsigned int* kreg, int lane,
                                            int wid, int* red) {
  unsigned int v = 0u;
  for (int bit = 31; bit >= 0; --bit) {
    const unsigned int cand = v | (1u << bit);
    int c = 0;
    #pragma unroll
    for (int f = 0; f < 8; ++f) c += (kreg[f] >= cand) ? 1 : 0;
    #pragma unroll
    for (int off = 1; off < 64; off <<= 1) c += __shfl_xor(c, off);
    if (lane == 0) red[wid] = c;
    __syncthreads();
    if (red[0] + red[1] + red[2] + red[3] >= NSEL) v = cand;
    __syncthreads();
  }
  return v;
}

// ---------------------------------------------------------------------------
// B1: radix pass 1 + boundary-band collection
// ---------------------------------------------------------------------------
__global__ __launch_bounds__(256) void radix1_kernel(const unsigned int* __restrict__ keysW,
                                                     int* __restrict__ Band,
                                                     int* __restrict__ nband) {
  __shared__ int red[4];
  __shared__ int cntS;
  const int b = blockIdx.x;
  const int tid = threadIdx.x;
  const int lane = tid & 63, wid = tid >> 6;
  const int base = tid * 8;

  unsigned int kreg[8];
  #pragma unroll
  for (int f = 0; f < 8; ++f) kreg[f] = keysW[(size_t)b * NN + base + f];
  if (tid == 0) cntS = 0;
  __syncthreads();

  const unsigned int v1 = radix_thresh(kreg, lane, wid, red);
  const float vf = dec(v1);

  #pragma unroll
  for (int f = 0; f < 8; ++f) {
    if (fabsf(dec(kreg[f]) - vf) <= EPSBAND) {
      int p = atomicAdd(&cntS, 1);
      Band[(size_t)b * NN + p] = base + f;
    }
  }
  __syncthreads();
  if (tid == 0) nband[b] = cntS;
}

// ---------------------------------------------------------------------------
// B2: exact fp32 rowmax recheck for band rows (one block per band row,
// strided loop if nband > MAXB). K[b] is 512 KB -> L2/L3-resident.
// ---------------------------------------------------------------------------
__global__ __launch_bounds__(256) void recheck_kernel(const float* __restrict__ Q,
                                                      const float* __restrict__ K,
                                                      const int* __restrict__ Band,
                                                      const int* __restrict__ nband,
                                                      const float* __restrict__ meanv,
                                                      unsigned int* __restrict__ keysW) {
  __shared__ float qsh[64];
  __shared__ float fred[4];
  const int b = blockIdx.y;
  const int nb_ = nband[b];
  const int tid = threadIdx.x;
  const int lane = tid & 63, wid = tid >> 6;

  for (int n = blockIdx.x; n < nb_; n += MAXB) {
    const int row = Band[(size_t)b * NN + n];
    __syncthreads();  // protect qsh reuse across loop iters
    if (tid < 64) qsh[tid] = Q[((size_t)b * NN + row) * DH + tid];
    __syncthreads();
    float lmax = -3.0e38f;
    for (int j = tid; j < NN; j += 256) {
      const float* krow = K + ((size_t)b * NN + j) * DH;
      float s = 0.f;
      #pragma unroll
      for (int d4 = 0; d4 < 16; ++d4) {
        float4 kv = *(const float4*)(krow + d4 * 4);
        s = fmaf(kv.x, qsh[d4 * 4 + 0], s);
        s = fmaf(kv.y, qsh[d4 * 4 + 1], s);
        s = fmaf(kv.z, qsh[d4 * 4 + 2], s);
        s = fmaf(kv.w, qsh[d4 * 4 + 3], s);
      }
      lmax = fmaxf(lmax, s);
    }
    #pragma unroll
    for (int off = 1; off < 64; off <<= 1)
      lmax = fmaxf(lmax, __shfl_xor(lmax, off));
    if (lane == 0) fred[wid] = lmax;
    __syncthreads();
    if (tid == 0) {
      const float mx = fmaxf(fmaxf(fred[0], fred[1]), fmaxf(fred[2], fred[3]));
      keysW[(size_t)b * NN + row] = enc(mx - meanv[(size_t)b * NN + row]);
    }
  }
}

// ---------------------------------------------------------------------------
// B3: radix pass 2 on corrected keys + compaction (set semantics, ties
// index-ascending).
// ---------------------------------------------------------------------------
__global__ __launch_bounds__(256) void radix2_kernel(const unsigned int* __restrict__ keysW,
                                                     int* __restrict__ Isel) {
  __shared__ int red[4];
  const int b = blockIdx.x;
  const int tid = threadIdx.x;
  const int lane = tid & 63, wid = tid >> 6;
  const int base = tid * 8;

  unsigned int kreg[8];
  #pragma unroll
  for (int f = 0; f < 8; ++f) kreg[f] = keysW[(size_t)b * NN + base + f];
  __syncthreads();

  const unsigned int v2 = radix_thresh(kreg, lane, wid, red);

  int flg[8];
  int cnt = 0;
  #pragma unroll
  for (int f = 0; f < 8; ++f) { flg[f] = (kreg[f] > v2) ? 1 : 0; cnt += flg[f]; }
  int scan = cnt;
  #pragma unroll
  for (int off = 1; off < 64; off <<= 1) {
    const int t = __shfl_up(scan, off);
    if (lane >= off) scan += t;
  }
  if (lane == 63) red[wid] = scan;
  __syncthreads();
  int wbase = 0;
  for (int ww = 0; ww < wid; ++ww) wbase += red[ww];
  const int cg = red[0] + red[1] + red[2] + red[3];
  int pos = wbase + scan - cnt;
  #pragma unroll
  for (int f = 0; f < 8; ++f)
    if (flg[f]) { Isel[b * NSEL + pos] = base + f; ++pos; }
  __syncthreads();

  const int need = NSEL - cg;
  cnt = 0;
  #pragma unroll
  for (int f = 0; f < 8; ++f) { flg[f] = (kreg[f] == v2) ? 1 : 0; cnt += flg[f]; }
  scan = cnt;
  #pragma unroll
  for (int off = 1; off < 64; off <<= 1) {
    const int t = __shfl_up(scan, off);
    if (lane >= off) scan += t;
  }
  if (lane == 63) red[wid] = scan;
  __syncthreads();
  wbase = 0;
  for (int ww = 0; ww < wid; ++ww) wbase += red[ww];
  pos = wbase + scan - cnt;
  #pragma unroll
  for (int f = 0; f < 8; ++f)
    if (flg[f]) {
      if (pos < need) Isel[b * NSEL + cg + pos] = base + f;
      ++pos;
    }
}

// ---------------------------------------------------------------------------
// Kernel C: fill out[b][i][:] = mean_d V[b][i][:]
// ---------------------------------------------------------------------------
__global__ __launch_bounds__(256) void fill_kernel(const float* __restrict__ V,
                                                   float* __restrict__ out) {
  const size_t row = (size_t)blockIdx.x * 4 + (threadIdx.x >> 6);
  const int lane = threadIdx.x & 63;
  float x = V[row * DH + lane];
  #pragma unroll
  for (int off = 1; off < 64; off <<= 1) x += __shfl_xor(x, off);
  out[row * DH + lane] = x * (1.0f / DH);
}

// ---------------------------------------------------------------------------
// Kernel D: flash partials, register-tiled (unchanged from round 5).
// ---------------------------------------------------------------------------
__global__ __launch_bounds__(256) void attn_part_kernel(const float* __restrict__ Q,
                                                        const float* __restrict__ K,
                                                        const float* __restrict__ V,
                                                        const int* __restrict__ Isel,
                                                        float* __restrict__ Pm,
                                                        float* __restrict__ Pl,
                                                        float* __restrict__ Po) {
  __shared__ float Qt[64][32];
  __shared__ float Kt[64][64];
  __shared__ float Vs[64][64];
  __shared__ float Pt[64][36];
  const int b = blockIdx.z;
  const int kc = blockIdx.y;
  const int g = blockIdx.x;
  const int tid = threadIdx.x;
  const int wq = tid >> 5;
  const int kx = tid & 31;

  if (tid < 128) {
    const int rr = tid >> 2;
    const int dblk = (tid & 3) * 16;
    const int lq = g * 32 + rr;
    const int qidx = (lq < NSEL) ? Isel[b * NSEL + lq] : 0;
    const float* qs = Q + ((size_t)b * NN + qidx) * DH + dblk;
    #pragma unroll
    for (int f = 0; f < 4; ++f) {
      float4 v = *reinterpret_cast<const float4*>(qs + f * 4);
      Qt[dblk + f * 4 + 0][rr] = v.x;
      Qt[dblk + f * 4 + 1][rr] = v.y;
      Qt[dblk + f * 4 + 2][rr] = v.z;
      Qt[dblk + f * 4 + 3][rr] = v.w;
    }
  }

  const float* Kb = K + ((size_t)b * NN + kc * CHUNK) * DH;
  const float* Vb = V + ((size_t)b * NN + kc * CHUNK) * DH;

  float m[4], lp[4], o[4][2];
  #pragma unroll
  for (int a = 0; a < 4; ++a) {
    m[a] = -3.0e38f; lp[a] = 0.f; o[a][0] = 0.f; o[a][1] = 0.f;
  }

  for (int st = 0; st < CHUNK / 64; ++st) {
    __syncthreads();
    {
      const int rr = tid & 63;
      const int dblk = (tid >> 6) * 16;
      const float* ks = Kb + ((size_t)(st * 64 + rr)) * DH + dblk;
      #pragma unroll
      for (int f = 0; f < 4; ++f) {
        float4 v = *reinterpret_cast<const float4*>(ks + f * 4);
        Kt[dblk + f * 4 + 0][rr] = v.x;
        Kt[dblk + f * 4 + 1][rr] = v.y;
        Kt[dblk + f * 4 + 2][rr] = v.z;
        Kt[dblk + f * 4 + 3][rr] = v.w;
      }
      const float* vsrc = Vb + (size_t)st * 64 * DH;
      float* vdst = &Vs[0][0];
      #pragma unroll
      for (int it = 0; it < 4; ++it) {
        const int fo = (it * 256 + tid) * 4;
        *reinterpret_cast<float4*>(vdst + fo) =
            *reinterpret_cast<const float4*>(vsrc + fo);
      }
    }
    __syncthreads();

    float sc[4][2];
    #pragma unroll
    for (int a = 0; a < 4; ++a) { sc[a][0] = 0.f; sc[a][1] = 0.f; }
    #pragma unroll 4
    for (int d = 0; d < 64; ++d) {
      float qv[4];
      *reinterpret_cast<float4*>(qv) =
          *reinterpret_cast<const float4*>(&Qt[d][wq * 4]);
      const float2 kv = *reinterpret_cast<const float2*>(&Kt[d][kx * 2]);
      #pragma unroll
      for (int a = 0; a < 4; ++a) {
        sc[a][0] = fmaf(qv[a], kv.x, sc[a][0]);
        sc[a][1] = fmaf(qv[a], kv.y, sc[a][1]);
      }
    }
    #pragma unroll
    for (int a = 0; a < 4; ++a) { sc[a][0] *= 0.125f; sc[a][1] *= 0.125f; }

    float tm[4];
    #pragma unroll
    for (int a = 0; a < 4; ++a) tm[a] = fmaxf(sc[a][0], sc[a][1]);
    #pragma unroll
    for (int off = 1; off < 32; off <<= 1) {
      #pragma unroll
      for (int a = 0; a < 4; ++a) tm[a] = fmaxf(tm[a], __shfl_xor(tm[a], off));
    }

    float w0[4], w1[4];
    #pragma unroll
    for (int a = 0; a < 4; ++a) {
      const float mn = fmaxf(m[a], tm[a]);
      const float scale = __expf(m[a] - mn);
      m[a] = mn;
      lp[a] *= scale;
      o[a][0] *= scale;
      o[a][1] *= scale;
      w0[a] = __expf(sc[a][0] - mn);
      w1[a] = __expf(sc[a][1] - mn);
      lp[a] += w0[a] + w1[a];
    }
    *reinterpret_cast<float4*>(&Pt[kx * 2][wq * 4]) =
        make_float4(w0[0], w0[1], w0[2], w0[3]);
    *reinterpret_cast<float4*>(&Pt[kx * 2 + 1][wq * 4]) =
        make_float4(w1[0], w1[1], w1[2], w1[3]);
    __syncthreads();

    #pragma unroll 4
    for (int k = 0; k < 64; ++k) {
      float pv[4];
      *reinterpret_cast<float4*>(pv) =
          *reinterpret_cast<const float4*>(&Pt[k][wq * 4]);
      const float2 vv = *reinterpret_cast<const float2*>(&Vs[k][kx * 2]);
      #pragma unroll
      for (int a = 0; a < 4; ++a) {
        o[a][0] = fmaf(pv[a], vv.x, o[a][0]);
        o[a][1] = fmaf(pv[a], vv.y, o[a][1]);
      }
    }
  }

  #pragma unroll
  for (int off = 1; off < 32; off <<= 1) {
    #pragma unroll
    for (int a = 0; a < 4; ++a) lp[a] += __shfl_xor(lp[a], off);
  }

  #pragma unroll
  for (int a = 0; a < 4; ++a) {
    const int lq = g * 32 + wq * 4 + a;
    if (lq < NSEL) {
      const size_t row = ((size_t)b * NSEL + lq) * KS + kc;
      if (kx == 0) { Pm[row] = m[a]; Pl[row] = lp[a]; }
      *reinterpret_cast<float2*>(Po + row * 64 + kx * 2) =
          make_float2(o[a][0], o[a][1]);
    }
  }
}

// ---------------------------------------------------------------------------
// Kernel E: merge the KS partials per selected row; write final output.
// ---------------------------------------------------------------------------
__global__ __launch_bounds__(256) void combine_kernel(const int* __restrict__ Isel,
                                                      const float* __restrict__ Pm,
                                                      const float* __restrict__ Pl,
                                                      const float* __restrict__ Po,
                                                      float* __restrict__ out) {
  const int r = blockIdx.x * 4 + (threadIdx.x >> 6);
  if (r >= NB * NSEL) return;
  const int lane = threadIdx.x & 63;
  const int b = r / NSEL;
  const int qidx = Isel[r];
  const size_t base = (size_t)r * KS;

  float pm[KS];
  float gm = -3.0e38f;
  #pragma unroll
  for (int c = 0; c < KS; ++c) { pm[c] = Pm[base + c]; gm = fmaxf(gm, pm[c]); }
  float L = 0.f, od = 0.f;
  #pragma unroll
  for (int c = 0; c < KS; ++c) {
    const float e = __expf(pm[c] - gm);
    L += Pl[base + c] * e;
    od += Po[(base + c) * 64 + lane] * e;
  }
  out[((size_t)b * NN + qidx) * DH + lane] = od / L;
}

// ---------------------------------------------------------------------------
extern "C" void kernel_launch(void* const* d_in, const int* in_sizes, int n_in,
                              void* d_out, int out_size, void* d_ws, size_t ws_size,
                              hipStream_t stream) {
  const float* Q = (const float*)d_in[0];
  const float* K = (const float*)d_in[1];
  const float* V = (const float*)d_in[2];
  // d_in[3] (seed) unused: U == n -> full permutation; max/mean are
  // permutation-invariant, so M equals rowmax - rowmean of the full QK^T.
  float* out = (float*)d_out;

  float* Mmax = (float*)d_ws;                                    // RS*NB*NN
  float* Kpart = Mmax + (size_t)RS * NB * NN;                    // NB*16*64
  unsigned int* keysW = (unsigned int*)(Kpart + (size_t)NB * 16 * 64);  // NB*NN
  float* meanv = (float*)(keysW + (size_t)NB * NN);              // NB*NN
  int* Band = (int*)(meanv + (size_t)NB * NN);                   // NB*NN
  int* nband = Band + (size_t)NB * NN;                           // NB (pad 16)
  int* Isel = nband + 16;                                        // NB*NSEL
  float* Pm = (float*)(Isel + NB * NSEL);                        // NB*NSEL*KS
  float* Pl = Pm + (size_t)NB * NSEL * KS;                       // NB*NSEL*KS
  float* Po = Pl + (size_t)NB * NSEL * KS;                       // NB*NSEL*KS*64
  unsigned short* Khi = (unsigned short*)(Po + (size_t)NB * NSEL * KS * 64);
  unsigned short* Klo = Khi + (size_t)NB * NN * DH;

  convk_kernel<<<dim3((NB * NN * DH) / (256 * 8)), 256, 0, stream>>>(K, Khi, Klo);
  kcolsum_kernel<<<dim3(16, NB), 256, 0, stream>>>(K, Kpart);
  rowstat_mfma<<<dim3(NN / 128, NB, RS), 256, 0, stream>>>(Q, Khi, Klo, Mmax);
  mstat_kernel<<<dim3(8, NB), 256, 0, stream>>>(Q, Mmax, Kpart, keysW, meanv);
  radix1_kernel<<<dim3(NB), 256, 0, stream>>>(keysW, Band, nband);
  recheck_kernel<<<dim3(MAXB, NB), 256, 0, stream>>>(Q, K, Band, nband, meanv, keysW);
  radix2_kernel<<<dim3(NB), 256, 0, stream>>>(keysW, Isel);
  fill_kernel<<<dim3(NB * NN / 4), 256, 0, stream>>>(V, out);
  attn_part_kernel<<<dim3(8, KS, NB), 256, 0, stream>>>(Q, K, V, Isel, Pm, Pl, Po);
  combine_kernel<<<dim3((NB * NSEL + 3) / 4), 256, 0, stream>>>(Isel, Pm, Pl, Po, out);
}

// Round 9
// 230.224 us; speedup vs baseline: 1.0794x; 1.0794x over previous
//
#include <hip/hip_runtime.h>

#define NB 16
#define NN 2048
#define DH 64
#define NSEL 228     // int(30 * ln(2048))
#define KS 8         // attention key-split chunks
#define CHUNK (NN / KS)
#define RS 4         // rowstat key-split
#define EPSBAND 2.0e-3f  // >> worst-case bf16x3 score error (~7e-4)
#define MAXB 32      // recheck blocks per batch (loops if nband > MAXB)

using s16x8 = __attribute__((ext_vector_type(8))) short;
using f32x16 = __attribute__((ext_vector_type(16))) float;

static __device__ __forceinline__ unsigned short f2bf(float x) {
  unsigned int u = __float_as_uint(x);
  u += 0x7fffu + ((u >> 16) & 1u);  // RNE; fine for finite data
  return (unsigned short)(u >> 16);
}
static __device__ __forceinline__ float bf2f(unsigned short h) {
  return __uint_as_float(((unsigned int)h) << 16);
}
static __device__ __forceinline__ unsigned int enc(float f) {
  unsigned int u = __float_as_uint(f);
  return (u & 0x80000000u) ? ~u : (u | 0x80000000u);
}
static __device__ __forceinline__ float dec(unsigned int k) {
  return (k & 0x80000000u) ? __uint_as_float(k & 0x7fffffffu)
                           : __uint_as_float(~k);
}

// ---------------------------------------------------------------------------
// K -> bf16 hi/lo split (used by rowstat_mfma AND attn_mfma scores)
// ---------------------------------------------------------------------------
__global__ __launch_bounds__(256) void convk_kernel(const float* __restrict__ K,
                                                    unsigned short* __restrict__ Khi,
                                                    unsigned short* __restrict__ Klo) {
  const size_t e = ((size_t)blockIdx.x * 256 + threadIdx.x) * 8;
  float4 a = *(const float4*)(K + e);
  float4 b = *(const float4*)(K + e + 4);
  float v[8] = {a.x, a.y, a.z, a.w, b.x, b.y, b.z, b.w};
  union { unsigned short u[8]; s16x8 s; } H, L;
  #pragma unroll
  for (int j = 0; j < 8; ++j) {
    unsigned short h = f2bf(v[j]);
    H.u[j] = h;
    L.u[j] = f2bf(v[j] - bf2f(h));
  }
  *(s16x8*)(Khi + e) = H.s;
  *(s16x8*)(Klo + e) = L.s;
}

// ---------------------------------------------------------------------------
// V -> transposed bf16 hi/lo split VT[b][d][n] (A-operand for attn PV MFMA)
// ---------------------------------------------------------------------------
__global__ __launch_bounds__(256) void convv_kernel(const float* __restrict__ V,
                                                    unsigned short* __restrict__ VThi,
                                                    unsigned short* __restrict__ VTlo) {
  __shared__ __align__(16) float T[64][65];
  const int b = blockIdx.y, ch = blockIdx.x;
  const int tid = threadIdx.x;
  {
    const int r = tid >> 2;
    const int c0 = (tid & 3) * 16;
    const float* src = V + ((size_t)b * NN + ch * 64 + r) * DH + c0;
    #pragma unroll
    for (int f = 0; f < 4; ++f) {
      float4 v = *(const float4*)(src + f * 4);
      T[r][c0 + f * 4 + 0] = v.x;
      T[r][c0 + f * 4 + 1] = v.y;
      T[r][c0 + f * 4 + 2] = v.z;
      T[r][c0 + f * 4 + 3] = v.w;
    }
  }
  __syncthreads();
  const int d = tid >> 2;
  const int j0 = (tid & 3) * 16;
  unsigned short* oh = VThi + ((size_t)b * DH + d) * NN + ch * 64 + j0;
  unsigned short* ol = VTlo + ((size_t)b * DH + d) * NN + ch * 64 + j0;
  #pragma unroll
  for (int half = 0; half < 2; ++half) {
    union { unsigned short u[8]; s16x8 s; } H, L;
    #pragma unroll
    for (int c = 0; c < 8; ++c) {
      const float v = T[j0 + half * 8 + c][d];
      const unsigned short hh = f2bf(v);
      H.u[c] = hh;
      L.u[c] = f2bf(v - bf2f(hh));
    }
    *(s16x8*)(oh + half * 8) = H.s;
    *(s16x8*)(ol + half * 8) = L.s;
  }
}

// ---------------------------------------------------------------------------
// Partial column sums of K (for the EXACT mean term: mean_i = q_i . Ksum / N)
// ---------------------------------------------------------------------------
__global__ __launch_bounds__(256) void kcolsum_kernel(const float* __restrict__ K,
                                                      float* __restrict__ Kpart) {
  __shared__ float part[4][64];
  const int b = blockIdx.y, ch = blockIdx.x;
  const int d = threadIdx.x & 63, g = threadIdx.x >> 6;
  const float* Kb = K + ((size_t)b * NN + ch * 128) * DH;
  float s = 0.f;
  for (int r = g; r < 128; r += 4) s += Kb[r * DH + d];
  part[g][d] = s;
  __syncthreads();
  if (threadIdx.x < 64)
    Kpart[((size_t)b * 16 + ch) * 64 + threadIdx.x] =
        part[0][threadIdx.x] + part[1][threadIdx.x] +
        part[2][threadIdx.x] + part[3][threadIdx.x];
}

// ---------------------------------------------------------------------------
// Kernel A (MFMA): rowmax of S = Q K^T over a 512-key chunk, bf16x3 split.
// (unchanged -- proven)
// ---------------------------------------------------------------------------
__global__ __launch_bounds__(256, 4) void rowstat_mfma(const float* __restrict__ Q,
                                                       const unsigned short* __restrict__ Khi,
                                                       const unsigned short* __restrict__ Klo,
                                                       float* __restrict__ Mmax) {
  __shared__ __align__(16) unsigned short KHs[128 * 64];
  __shared__ __align__(16) unsigned short KLs[128 * 64];
  const int b = blockIdx.y, cz = blockIdx.z;
  const int qbase = blockIdx.x * 128;
  const int tid = threadIdx.x;
  const int w = tid >> 6, lane = tid & 63;
  const int l31 = lane & 31, hi5 = lane >> 5;

  s16x8 qh[4], ql[4];
  {
    const float* qrow = Q + ((size_t)b * NN + qbase + w * 32 + l31) * DH;
    #pragma unroll
    for (int ks = 0; ks < 4; ++ks) {
      const int d0 = ks * 16 + hi5 * 8;
      float4 x = *(const float4*)(qrow + d0);
      float4 y = *(const float4*)(qrow + d0 + 4);
      float v[8] = {x.x, x.y, x.z, x.w, y.x, y.y, y.z, y.w};
      union { unsigned short u[8]; s16x8 s; } H, L;
      #pragma unroll
      for (int j = 0; j < 8; ++j) {
        unsigned short h = f2bf(v[j]);
        H.u[j] = h;
        L.u[j] = f2bf(v[j] - bf2f(h));
      }
      qh[ks] = H.s;
      ql[ks] = L.s;
    }
  }

  const size_t kbase = ((size_t)b * NN + cz * (NN / RS)) * DH;
  f32x16 vmax;
  #pragma unroll
  for (int i = 0; i < 16; ++i) vmax[i] = -3.0e38f;

  const int sr = tid >> 1;
  const int sh = tid & 1;

  for (int stage = 0; stage < NN / RS / 128; ++stage) {
    __syncthreads();
    {
      const size_t g = kbase + (size_t)(stage * 128 + sr) * DH + sh * 32;
      const unsigned short* gh = Khi + g;
      const unsigned short* gl = Klo + g;
      #pragma unroll
      for (int c = 0; c < 4; ++c) {
        s16x8 hv = *(const s16x8*)(gh + c * 8);
        s16x8 lv = *(const s16x8*)(gl + c * 8);
        const int chn = (sh * 4 + c) ^ (sr & 7);
        *(s16x8*)&KHs[(sr * 8 + chn) * 8] = hv;
        *(s16x8*)&KLs[(sr * 8 + chn) * 8] = lv;
      }
    }
    __syncthreads();

    #pragma unroll
    for (int ksub = 0; ksub < 4; ++ksub) {
      const int kr = ksub * 32 + l31;
      f32x16 acc;
      #pragma unroll
      for (int i = 0; i < 16; ++i) acc[i] = 0.f;
      #pragma unroll
      for (int ks = 0; ks < 4; ++ks) {
        const int chn = (ks * 2 + hi5) ^ (kr & 7);
        s16x8 ah = *(const s16x8*)&KHs[(kr * 8 + chn) * 8];
        s16x8 al = *(const s16x8*)&KLs[(kr * 8 + chn) * 8];
        acc = __builtin_amdgcn_mfma_f32_32x32x16_bf16(ah, qh[ks], acc, 0, 0, 0);
        acc = __builtin_amdgcn_mfma_f32_32x32x16_bf16(al, qh[ks], acc, 0, 0, 0);
        acc = __builtin_amdgcn_mfma_f32_32x32x16_bf16(ah, ql[ks], acc, 0, 0, 0);
      }
      #pragma unroll
      for (int i = 0; i < 16; ++i) vmax[i] = fmaxf(vmax[i], acc[i]);
    }
  }

  float m = vmax[0];
  #pragma unroll
  for (int i = 1; i < 16; ++i) m = fmaxf(m, vmax[i]);
  m = fmaxf(m, __shfl_xor(m, 32));
  if (lane < 32)
    Mmax[((size_t)cz * NB + b) * NN + qbase + w * 32 + lane] = m;
}

// ---------------------------------------------------------------------------
// B0: keys + mean for all rows (parallel, 128 blocks)
// ---------------------------------------------------------------------------
__global__ __launch_bounds__(256) void mstat_kernel(const float* __restrict__ Q,
                                                    const float* __restrict__ Mmax,
                                                    const float* __restrict__ Kpart,
                                                    unsigned int* __restrict__ keysW,
                                                    float* __restrict__ meanv) {
  __shared__ float Ksl[64];
  const int b = blockIdx.y;
  const int seg = blockIdx.x;
  const int tid = threadIdx.x;
  if (tid < 64) {
    float s = 0.f;
    #pragma unroll
    for (int c = 0; c < 16; ++c) s += Kpart[((size_t)b * 16 + c) * 64 + tid];
    Ksl[tid] = s;
  }
  __syncthreads();
  const int i = seg * 256 + tid;
  float mv = -3.0e38f;
  #pragma unroll
  for (int cz = 0; cz < RS; ++cz)
    mv = fmaxf(mv, Mmax[((size_t)cz * NB + b) * NN + i]);
  const float* qrow = Q + ((size_t)b * NN + i) * DH;
  float s = 0.f;
  #pragma unroll
  for (int d4 = 0; d4 < 16; ++d4) {
    float4 qv = *(const float4*)(qrow + d4 * 4);
    s = fmaf(qv.x, Ksl[d4 * 4 + 0], s);
    s = fmaf(qv.y, Ksl[d4 * 4 + 1], s);
    s = fmaf(qv.z, Ksl[d4 * 4 + 2], s);
    s = fmaf(qv.w, Ksl[d4 * 4 + 3], s);
  }
  const float mean = s * (1.0f / NN);
  meanv[(size_t)b * NN + i] = mean;
  keysW[(size_t)b * NN + i] = enc(mv - mean);
}

// ---------------------------------------------------------------------------
// shared radix helper
// ---------------------------------------------------------------------------
static __device__ unsigned int radix_thresh(const unsigned int* kreg, int lane,
                                            int wid, int* red) {
  unsigned int v = 0u;
  for (int bit = 31; bit >= 0; --bit) {
    const unsigned int cand = v | (1u << bit);
    int c = 0;
    #pragma unroll
    for (int f = 0; f < 8; ++f) c += (kreg[f] >= cand) ? 1 : 0;
    #pragma unroll
    for (int off = 1; off < 64; off <<= 1) c += __shfl_xor(c, off);
    if (lane == 0) red[wid] = c;
    __syncthreads();
    if (red[0] + red[1] + red[2] + red[3] >= NSEL) v = cand;
    __syncthreads();
  }
  return v;
}

// ---------------------------------------------------------------------------
// B1: radix pass 1 + boundary-band collection
// ---------------------------------------------------------------------------
__global__ __launch_bounds__(256) void radix1_kernel(const unsigned int* __restrict__ keysW,
                                                     int* __restrict__ Band,
                                                     int* __restrict__ nband) {
  __shared__ int red[4];
  __shared__ int cntS;
  const int b = blockIdx.x;
  const int tid = threadIdx.x;
  const int lane = tid & 63, wid = tid >> 6;
  const int base = tid * 8;

  unsigned int kreg[8];
  #pragma unroll
  for (int f = 0; f < 8; ++f) kreg[f] = keysW[(size_t)b * NN + base + f];
  if (tid == 0) cntS = 0;
  __syncthreads();

  const unsigned int v1 = radix_thresh(kreg, lane, wid, red);
  const float vf = dec(v1);

  #pragma unroll
  for (int f = 0; f < 8; ++f) {
    if (fabsf(dec(kreg[f]) - vf) <= EPSBAND) {
      int p = atomicAdd(&cntS, 1);
      Band[(size_t)b * NN + p] = base + f;
    }
  }
  __syncthreads();
  if (tid == 0) nband[b] = cntS;
}

// ---------------------------------------------------------------------------
// B2: exact fp32 rowmax recheck for band rows
// ---------------------------------------------------------------------------
__global__ __launch_bounds__(256) void recheck_kernel(const float* __restrict__ Q,
                                                      const float* __restrict__ K,
                                                      const int* __restrict__ Band,
                                                      const int* __restrict__ nband,
                                                      const float* __restrict__ meanv,
                                                      unsigned int* __restrict__ keysW) {
  __shared__ float qsh[64];
  __shared__ float fred[4];
  const int b = blockIdx.y;
  const int nb_ = nband[b];
  const int tid = threadIdx.x;
  const int lane = tid & 63, wid = tid >> 6;

  for (int n = blockIdx.x; n < nb_; n += MAXB) {
    const int row = Band[(size_t)b * NN + n];
    __syncthreads();
    if (tid < 64) qsh[tid] = Q[((size_t)b * NN + row) * DH + tid];
    __syncthreads();
    float lmax = -3.0e38f;
    for (int j = tid; j < NN; j += 256) {
      const float* krow = K + ((size_t)b * NN + j) * DH;
      float s = 0.f;
      #pragma unroll
      for (int d4 = 0; d4 < 16; ++d4) {
        float4 kv = *(const float4*)(krow + d4 * 4);
        s = fmaf(kv.x, qsh[d4 * 4 + 0], s);
        s = fmaf(kv.y, qsh[d4 * 4 + 1], s);
        s = fmaf(kv.z, qsh[d4 * 4 + 2], s);
        s = fmaf(kv.w, qsh[d4 * 4 + 3], s);
      }
      lmax = fmaxf(lmax, s);
    }
    #pragma unroll
    for (int off = 1; off < 64; off <<= 1)
      lmax = fmaxf(lmax, __shfl_xor(lmax, off));
    if (lane == 0) fred[wid] = lmax;
    __syncthreads();
    if (tid == 0) {
      const float mx = fmaxf(fmaxf(fred[0], fred[1]), fmaxf(fred[2], fred[3]));
      keysW[(size_t)b * NN + row] = enc(mx - meanv[(size_t)b * NN + row]);
    }
  }
}

// ---------------------------------------------------------------------------
// B3: radix pass 2 + compaction (set semantics, ties index-ascending)
// ---------------------------------------------------------------------------
__global__ __launch_bounds__(256) void radix2_kernel(const unsigned int* __restrict__ keysW,
                                                     int* __restrict__ Isel) {
  __shared__ int red[4];
  const int b = blockIdx.x;
  const int tid = threadIdx.x;
  const int lane = tid & 63, wid = tid >> 6;
  const int base = tid * 8;

  unsigned int kreg[8];
  #pragma unroll
  for (int f = 0; f < 8; ++f) kreg[f] = keysW[(size_t)b * NN + base + f];
  __syncthreads();

  const unsigned int v2 = radix_thresh(kreg, lane, wid, red);

  int flg[8];
  int cnt = 0;
  #pragma unroll
  for (int f = 0; f < 8; ++f) { flg[f] = (kreg[f] > v2) ? 1 : 0; cnt += flg[f]; }
  int scan = cnt;
  #pragma unroll
  for (int off = 1; off < 64; off <<= 1) {
    const int t = __shfl_up(scan, off);
    if (lane >= off) scan += t;
  }
  if (lane == 63) red[wid] = scan;
  __syncthreads();
  int wbase = 0;
  for (int ww = 0; ww < wid; ++ww) wbase += red[ww];
  const int cg = red[0] + red[1] + red[2] + red[3];
  int pos = wbase + scan - cnt;
  #pragma unroll
  for (int f = 0; f < 8; ++f)
    if (flg[f]) { Isel[b * NSEL + pos] = base + f; ++pos; }
  __syncthreads();

  const int need = NSEL - cg;
  cnt = 0;
  #pragma unroll
  for (int f = 0; f < 8; ++f) { flg[f] = (kreg[f] == v2) ? 1 : 0; cnt += flg[f]; }
  scan = cnt;
  #pragma unroll
  for (int off = 1; off < 64; off <<= 1) {
    const int t = __shfl_up(scan, off);
    if (lane >= off) scan += t;
  }
  if (lane == 63) red[wid] = scan;
  __syncthreads();
  wbase = 0;
  for (int ww = 0; ww < wid; ++ww) wbase += red[ww];
  pos = wbase + scan - cnt;
  #pragma unroll
  for (int f = 0; f < 8; ++f)
    if (flg[f]) {
      if (pos < need) Isel[b * NSEL + cg + pos] = base + f;
      ++pos;
    }
}

// ---------------------------------------------------------------------------
// Kernel C: fill out[b][i][:] = mean_d V[b][i][:]
// ---------------------------------------------------------------------------
__global__ __launch_bounds__(256) void fill_kernel(const float* __restrict__ V,
                                                   float* __restrict__ out) {
  const size_t row = (size_t)blockIdx.x * 4 + (threadIdx.x >> 6);
  const int lane = threadIdx.x & 63;
  float x = V[row * DH + lane];
  #pragma unroll
  for (int off = 1; off < 64; off <<= 1) x += __shfl_xor(x, off);
  out[row * DH + lane] = x * (1.0f / DH);
}

// ---------------------------------------------------------------------------
// Kernel D (MFMA): flash partials via bf16x3 matrix cores.
// Block: 32 selected queries x 256-key chunk; 4 waves, each owns 64 keys.
// Scores: S[k][q] = mfma(K-frag, Q-frag) -- identical conventions to
// rowstat_mfma (C: q=lane&31, k=(r&3)+8*(r>>2)+4h; verified end-to-end).
// Softmax: q is lane-local -> per-lane max/sum + shfl_xor(32) + tiny LDS
// cross-wave reduce; single exact max per chunk (no online rescale).
// PV: O^T[d][q] = sum_k VT[d][k] * P^T[k][q]. A = VT (pre-transposed bf16
// hi/lo). B = P^T rebuilt in-register from the C layout: for kstep
// (t,kb) row kdim = kb*16+h*8+j, lane needs own regs kb*8+0..3 and the
// partner half-wave's (shfl_xor 32); h=0 takes [own, partner], h=1
// [partner, own] per the crow() formula. P split hi/lo (bf16x3) keeps
// PV error ~1e-5.
// ---------------------------------------------------------------------------
__global__ __launch_bounds__(256, 2) void attn_mfma(const float* __restrict__ Q,
                                                    const unsigned short* __restrict__ Khi,
                                                    const unsigned short* __restrict__ Klo,
                                                    const unsigned short* __restrict__ VThi,
                                                    const unsigned short* __restrict__ VTlo,
                                                    const int* __restrict__ Isel,
                                                    float* __restrict__ Pm,
                                                    float* __restrict__ Pl,
                                                    float* __restrict__ Po) {
  __shared__ float wmax[4][32];
  __shared__ float wl[4][32];
  __shared__ __align__(16) float Opart[4][32][68];  // pad 68: spread banks
  const int b = blockIdx.z, kc = blockIdx.y, g = blockIdx.x;
  const int tid = threadIdx.x, w = tid >> 6, lane = tid & 63;
  const int l31 = lane & 31, h = lane >> 5;

  // --- Q B-fragments (bf16 hi/lo split, on the fly) ---
  const int lq = g * 32 + l31;
  const int qidx = (lq < NSEL) ? Isel[b * NSEL + lq] : Isel[b * NSEL];
  s16x8 qbh[4], qbl[4];
  {
    const float* qr = Q + ((size_t)b * NN + qidx) * DH;
    #pragma unroll
    for (int s = 0; s < 4; ++s) {
      const int d0 = s * 16 + h * 8;
      float4 x = *(const float4*)(qr + d0);
      float4 y = *(const float4*)(qr + d0 + 4);
      float v[8] = {x.x, x.y, x.z, x.w, y.x, y.y, y.z, y.w};
      union { unsigned short u[8]; s16x8 s8; } H, L;
      #pragma unroll
      for (int j = 0; j < 8; ++j) {
        const unsigned short hh = f2bf(v[j]);
        H.u[j] = hh;
        L.u[j] = f2bf(v[j] - bf2f(hh));
      }
      qbh[s] = H.s8;
      qbl[s] = L.s8;
    }
  }

  // --- scores: 2 k-tiles of 32, bf16x3 ---
  const size_t krow0 = (size_t)b * NN + kc * CHUNK + w * 64;
  f32x16 p[2];
  #pragma unroll
  for (int t = 0; t < 2; ++t) {
    const unsigned short* kh = Khi + (krow0 + t * 32 + l31) * DH + h * 8;
    const unsigned short* kl = Klo + (krow0 + t * 32 + l31) * DH + h * 8;
    f32x16 acc;
    #pragma unroll
    for (int i = 0; i < 16; ++i) acc[i] = 0.f;
    #pragma unroll
    for (int s = 0; s < 4; ++s) {
      const s16x8 ah = *(const s16x8*)(kh + s * 16);
      const s16x8 al = *(const s16x8*)(kl + s * 16);
      acc = __builtin_amdgcn_mfma_f32_32x32x16_bf16(ah, qbh[s], acc, 0, 0, 0);
      acc = __builtin_amdgcn_mfma_f32_32x32x16_bf16(al, qbh[s], acc, 0, 0, 0);
      acc = __builtin_amdgcn_mfma_f32_32x32x16_bf16(ah, qbl[s], acc, 0, 0, 0);
    }
    p[t] = acc;
  }

  // --- chunk max per q (q = l31 is lane-local) ---
  float rmax = p[0][0];
  #pragma unroll
  for (int i = 1; i < 16; ++i) rmax = fmaxf(rmax, p[0][i]);
  #pragma unroll
  for (int i = 0; i < 16; ++i) rmax = fmaxf(rmax, p[1][i]);
  rmax = fmaxf(rmax, __shfl_xor(rmax, 32));
  if (lane < 32) wmax[w][lane] = rmax;
  __syncthreads();
  const float gmax = fmaxf(fmaxf(wmax[0][l31], wmax[1][l31]),
                           fmaxf(wmax[2][l31], wmax[3][l31]));
  const float m = gmax * 0.125f;  // scaled max (1/sqrt(64))

  // --- P = exp(s*0.125 - m); partial l ---
  float lsum = 0.f;
  #pragma unroll
  for (int t = 0; t < 2; ++t)
    #pragma unroll
    for (int i = 0; i < 16; ++i) {
      const float e = __expf(fmaf(p[t][i], 0.125f, -m));
      p[t][i] = e;
      lsum += e;
    }
  lsum += __shfl_xor(lsum, 32);
  if (lane < 32) wl[w][lane] = lsum;

  // --- PV: per 16-k step build P^T B-frag (hi+lo) and MFMA with VT ---
  f32x16 oacc[2];
  #pragma unroll
  for (int i = 0; i < 16; ++i) { oacc[0][i] = 0.f; oacc[1][i] = 0.f; }

  #pragma unroll
  for (int s = 0; s < 4; ++s) {
    const int t = s >> 1, kb = s & 1;
    float pr[8];
    #pragma unroll
    for (int j = 0; j < 8; ++j) pr[j] = p[t][kb * 8 + j];
    unsigned int ah[4], al[4];
    #pragma unroll
    for (int pi = 0; pi < 4; ++pi) {
      const unsigned short h0 = f2bf(pr[pi * 2]);
      const unsigned short h1 = f2bf(pr[pi * 2 + 1]);
      ah[pi] = (unsigned int)h0 | ((unsigned int)h1 << 16);
      al[pi] = (unsigned int)f2bf(pr[pi * 2] - bf2f(h0)) |
               ((unsigned int)f2bf(pr[pi * 2 + 1] - bf2f(h1)) << 16);
    }
    unsigned int sh_[4], sl_[4];
    #pragma unroll
    for (int pi = 0; pi < 4; ++pi) {
      sh_[pi] = (unsigned int)__shfl_xor((int)ah[pi], 32);
      sl_[pi] = (unsigned int)__shfl_xor((int)al[pi], 32);
    }
    union { int4 i4; s16x8 s8; } BH, BL;
    if (h == 0) {
      BH.i4 = make_int4((int)ah[0], (int)ah[1], (int)sh_[0], (int)sh_[1]);
      BL.i4 = make_int4((int)al[0], (int)al[1], (int)sl_[0], (int)sl_[1]);
    } else {
      BH.i4 = make_int4((int)sh_[2], (int)sh_[3], (int)ah[2], (int)ah[3]);
      BL.i4 = make_int4((int)sl_[2], (int)sl_[3], (int)al[2], (int)al[3]);
    }
    const size_t koff = (size_t)kc * CHUNK + w * 64 + s * 16 + h * 8;
    #pragma unroll
    for (int dt = 0; dt < 2; ++dt) {
      const size_t vrow = ((size_t)b * DH + dt * 32 + l31) * NN + koff;
      const s16x8 av = *(const s16x8*)(VThi + vrow);
      const s16x8 avl = *(const s16x8*)(VTlo + vrow);
      oacc[dt] = __builtin_amdgcn_mfma_f32_32x32x16_bf16(av, BH.s8, oacc[dt], 0, 0, 0);
      oacc[dt] = __builtin_amdgcn_mfma_f32_32x32x16_bf16(av, BL.s8, oacc[dt], 0, 0, 0);
      oacc[dt] = __builtin_amdgcn_mfma_f32_32x32x16_bf16(avl, BH.s8, oacc[dt], 0, 0, 0);
    }
  }

  // --- write per-wave O partial: lane holds q=l31, d=(r&3)+8(r>>2)+4h+32dt ---
  #pragma unroll
  for (int dt = 0; dt < 2; ++dt)
    #pragma unroll
    for (int rg = 0; rg < 4; ++rg) {
      const int d0 = dt * 32 + rg * 8 + h * 4;
      float4 vv;
      vv.x = oacc[dt][rg * 4 + 0];
      vv.y = oacc[dt][rg * 4 + 1];
      vv.z = oacc[dt][rg * 4 + 2];
      vv.w = oacc[dt][rg * 4 + 3];
      *(float4*)&Opart[w][l31][d0] = vv;
    }
  __syncthreads();

  // --- cross-wave reduce + writeout ---
  const int q = tid >> 3, dg = (tid & 7) * 8;
  float4 s0, s1;
  s0.x = s0.y = s0.z = s0.w = 0.f;
  s1.x = s1.y = s1.z = s1.w = 0.f;
  #pragma unroll
  for (int ww = 0; ww < 4; ++ww) {
    const float4 a = *(const float4*)&Opart[ww][q][dg];
    const float4 c = *(const float4*)&Opart[ww][q][dg + 4];
    s0.x += a.x; s0.y += a.y; s0.z += a.z; s0.w += a.w;
    s1.x += c.x; s1.y += c.y; s1.z += c.z; s1.w += c.w;
  }
  const int lq2 = g * 32 + q;
  if (lq2 < NSEL) {
    const size_t row = ((size_t)b * NSEL + lq2) * KS + kc;
    *(float4*)(Po + row * 64 + dg) = s0;
    *(float4*)(Po + row * 64 + dg + 4) = s1;
    if (dg == 0) {
      const float gm2 = fmaxf(fmaxf(wmax[0][q], wmax[1][q]),
                              fmaxf(wmax[2][q], wmax[3][q]));
      Pm[row] = gm2 * 0.125f;
      Pl[row] = wl[0][q] + wl[1][q] + wl[2][q] + wl[3][q];
    }
  }
}

// ---------------------------------------------------------------------------
// Kernel E: merge the KS partials per selected row; write final output.
// ---------------------------------------------------------------------------
__global__ __launch_bounds__(256) void combine_kernel(const int* __restrict__ Isel,
                                                      const float* __restrict__ Pm,
                                                      const float* __restrict__ Pl,
                                                      const float* __restrict__ Po,
                                                      float* __restrict__ out) {
  const int r = blockIdx.x * 4 + (threadIdx.x >> 6);
  if (r >= NB * NSEL) return;
  const int lane = threadIdx.x & 63;
  const int b = r / NSEL;
  const int qidx = Isel[r];
  const size_t base = (size_t)r * KS;

  float pm[KS];
  float gm = -3.0e38f;
  #pragma unroll
  for (int c = 0; c < KS; ++c) { pm[c] = Pm[base + c]; gm = fmaxf(gm, pm[c]); }
  float L = 0.f, od = 0.f;
  #pragma unroll
  for (int c = 0; c < KS; ++c) {
    const float e = __expf(pm[c] - gm);
    L += Pl[base + c] * e;
    od += Po[(base + c) * 64 + lane] * e;
  }
  out[((size_t)b * NN + qidx) * DH + lane] = od / L;
}

// ---------------------------------------------------------------------------
extern "C" void kernel_launch(void* const* d_in, const int* in_sizes, int n_in,
                              void* d_out, int out_size, void* d_ws, size_t ws_size,
                              hipStream_t stream) {
  const float* Q = (const float*)d_in[0];
  const float* K = (const float*)d_in[1];
  const float* V = (const float*)d_in[2];
  // d_in[3] (seed) unused: U == n -> full permutation; max/mean are
  // permutation-invariant, so M equals rowmax - rowmean of the full QK^T.
  float* out = (float*)d_out;

  float* Mmax = (float*)d_ws;                                    // RS*NB*NN
  float* Kpart = Mmax + (size_t)RS * NB * NN;                    // NB*16*64
  unsigned int* keysW = (unsigned int*)(Kpart + (size_t)NB * 16 * 64);  // NB*NN
  float* meanv = (float*)(keysW + (size_t)NB * NN);              // NB*NN
  int* Band = (int*)(meanv + (size_t)NB * NN);                   // NB*NN
  int* nband = Band + (size_t)NB * NN;                           // NB (pad 16)
  int* Isel = nband + 16;                                        // NB*NSEL
  float* Pm = (float*)(Isel + NB * NSEL);                        // NB*NSEL*KS
  float* Pl = Pm + (size_t)NB * NSEL * KS;                       // NB*NSEL*KS
  float* Po = Pl + (size_t)NB * NSEL * KS;                       // NB*NSEL*KS*64
  unsigned short* Khi = (unsigned short*)(Po + (size_t)NB * NSEL * KS * 64);
  unsigned short* Klo = Khi + (size_t)NB * NN * DH;
  unsigned short* VThi = Klo + (size_t)NB * NN * DH;
  unsigned short* VTlo = VThi + (size_t)NB * NN * DH;

  convk_kernel<<<dim3((NB * NN * DH) / (256 * 8)), 256, 0, stream>>>(K, Khi, Klo);
  convv_kernel<<<dim3(NN / 64, NB), 256, 0, stream>>>(V, VThi, VTlo);
  kcolsum_kernel<<<dim3(16, NB), 256, 0, stream>>>(K, Kpart);
  rowstat_mfma<<<dim3(NN / 128, NB, RS), 256, 0, stream>>>(Q, Khi, Klo, Mmax);
  mstat_kernel<<<dim3(8, NB), 256, 0, stream>>>(Q, Mmax, Kpart, keysW, meanv);
  radix1_kernel<<<dim3(NB), 256, 0, stream>>>(keysW, Band, nband);
  recheck_kernel<<<dim3(MAXB, NB), 256, 0, stream>>>(Q, K, Band, nband, meanv, keysW);
  radix2_kernel<<<dim3(NB), 256, 0, stream>>>(keysW, Isel);
  fill_kernel<<<dim3(NB * NN / 4), 256, 0, stream>>>(V, out);
  attn_mfma<<<dim3(8, KS, NB), 256, 0, stream>>>(Q, Khi, Klo, VThi, VTlo, Isel,
                                                 Pm, Pl, Po);
  combine_kernel<<<dim3((NB * NSEL + 3) / 4), 256, 0, stream>>>(Isel, Pm, Pl, Po, out);
}

// Round 10
// 222.125 us; speedup vs baseline: 1.1188x; 1.0365x over previous
//
#include <hip/hip_runtime.h>

#define NB 16
#define NN 2048
#define DH 64
#define NSEL 228     // int(30 * ln(2048))
#define KS 4         // attention key-split chunks
#define CHUNK (NN / KS)
#define RS 4         // rowstat key-split
#define EPSBAND 2.0e-3f  // >> worst-case bf16x3 score error (~7e-4)
#define MAXB 32      // recheck blocks per batch (loops if nband > MAXB)

using s16x8 = __attribute__((ext_vector_type(8))) short;
using f32x16 = __attribute__((ext_vector_type(16))) float;

static __device__ __forceinline__ unsigned short f2bf(float x) {
  unsigned int u = __float_as_uint(x);
  u += 0x7fffu + ((u >> 16) & 1u);  // RNE; fine for finite data
  return (unsigned short)(u >> 16);
}
static __device__ __forceinline__ float bf2f(unsigned short h) {
  return __uint_as_float(((unsigned int)h) << 16);
}
static __device__ __forceinline__ unsigned int enc(float f) {
  unsigned int u = __float_as_uint(f);
  return (u & 0x80000000u) ? ~u : (u | 0x80000000u);
}
static __device__ __forceinline__ float dec(unsigned int k) {
  return (k & 0x80000000u) ? __uint_as_float(k & 0x7fffffffu)
                           : __uint_as_float(~k);
}

// ---------------------------------------------------------------------------
// Fused conversions (one kernel, z = mode):
//   mode 0: K 64-row chunk -> Khi/Klo (layout preserved) + partial colsums
//   mode 1: V 64-row chunk -> VThi/VTlo (transposed)
// ---------------------------------------------------------------------------
__global__ __launch_bounds__(256) void conv_fused(const float* __restrict__ K,
                                                  const float* __restrict__ V,
                                                  unsigned short* __restrict__ Khi,
                                                  unsigned short* __restrict__ Klo,
                                                  unsigned short* __restrict__ VThi,
                                                  unsigned short* __restrict__ VTlo,
                                                  float* __restrict__ Kpart) {
  __shared__ __align__(16) float T[64][65];
  const int b = blockIdx.y, ch = blockIdx.x;
  const int tid = threadIdx.x;
  const int r = tid >> 2;
  const int c0 = (tid & 3) * 16;

  if (blockIdx.z == 0) {
    // --- K mode ---
    const size_t off = ((size_t)b * NN + ch * 64 + r) * DH + c0;
    const float* src = K + off;
    float v[16];
    #pragma unroll
    for (int f = 0; f < 4; ++f) {
      float4 x = *(const float4*)(src + f * 4);
      v[f * 4 + 0] = x.x; v[f * 4 + 1] = x.y;
      v[f * 4 + 2] = x.z; v[f * 4 + 3] = x.w;
      T[r][c0 + f * 4 + 0] = x.x;
      T[r][c0 + f * 4 + 1] = x.y;
      T[r][c0 + f * 4 + 2] = x.z;
      T[r][c0 + f * 4 + 3] = x.w;
    }
    #pragma unroll
    for (int half = 0; half < 2; ++half) {
      union { unsigned short u[8]; s16x8 s; } H, L;
      #pragma unroll
      for (int j = 0; j < 8; ++j) {
        const float x = v[half * 8 + j];
        const unsigned short hh = f2bf(x);
        H.u[j] = hh;
        L.u[j] = f2bf(x - bf2f(hh));
      }
      *(s16x8*)(Khi + off + half * 8) = H.s;
      *(s16x8*)(Klo + off + half * 8) = L.s;
    }
    __syncthreads();
    if (tid < 64) {
      float s = 0.f;
      #pragma unroll 8
      for (int rr = 0; rr < 64; ++rr) s += T[rr][tid];
      Kpart[((size_t)b * 32 + ch) * 64 + tid] = s;
    }
  } else {
    // --- V mode (transpose) ---
    const float* src = V + ((size_t)b * NN + ch * 64 + r) * DH + c0;
    #pragma unroll
    for (int f = 0; f < 4; ++f) {
      float4 x = *(const float4*)(src + f * 4);
      T[r][c0 + f * 4 + 0] = x.x;
      T[r][c0 + f * 4 + 1] = x.y;
      T[r][c0 + f * 4 + 2] = x.z;
      T[r][c0 + f * 4 + 3] = x.w;
    }
    __syncthreads();
    const int d = tid >> 2;
    const int j0 = (tid & 3) * 16;
    unsigned short* oh = VThi + ((size_t)b * DH + d) * NN + ch * 64 + j0;
    unsigned short* ol = VTlo + ((size_t)b * DH + d) * NN + ch * 64 + j0;
    #pragma unroll
    for (int half = 0; half < 2; ++half) {
      union { unsigned short u[8]; s16x8 s; } H, L;
      #pragma unroll
      for (int c = 0; c < 8; ++c) {
        const float x = T[j0 + half * 8 + c][d];
        const unsigned short hh = f2bf(x);
        H.u[c] = hh;
        L.u[c] = f2bf(x - bf2f(hh));
      }
      *(s16x8*)(oh + half * 8) = H.s;
      *(s16x8*)(ol + half * 8) = L.s;
    }
  }
}

// ---------------------------------------------------------------------------
// Kernel A (MFMA): rowmax of S = Q K^T over a 512-key chunk, bf16x3 split.
// (proven; unchanged)
// ---------------------------------------------------------------------------
__global__ __launch_bounds__(256, 4) void rowstat_mfma(const float* __restrict__ Q,
                                                       const unsigned short* __restrict__ Khi,
                                                       const unsigned short* __restrict__ Klo,
                                                       float* __restrict__ Mmax) {
  __shared__ __align__(16) unsigned short KHs[128 * 64];
  __shared__ __align__(16) unsigned short KLs[128 * 64];
  const int b = blockIdx.y, cz = blockIdx.z;
  const int qbase = blockIdx.x * 128;
  const int tid = threadIdx.x;
  const int w = tid >> 6, lane = tid & 63;
  const int l31 = lane & 31, hi5 = lane >> 5;

  s16x8 qh[4], ql[4];
  {
    const float* qrow = Q + ((size_t)b * NN + qbase + w * 32 + l31) * DH;
    #pragma unroll
    for (int ks = 0; ks < 4; ++ks) {
      const int d0 = ks * 16 + hi5 * 8;
      float4 x = *(const float4*)(qrow + d0);
      float4 y = *(const float4*)(qrow + d0 + 4);
      float v[8] = {x.x, x.y, x.z, x.w, y.x, y.y, y.z, y.w};
      union { unsigned short u[8]; s16x8 s; } H, L;
      #pragma unroll
      for (int j = 0; j < 8; ++j) {
        unsigned short h = f2bf(v[j]);
        H.u[j] = h;
        L.u[j] = f2bf(v[j] - bf2f(h));
      }
      qh[ks] = H.s;
      ql[ks] = L.s;
    }
  }

  const size_t kbase = ((size_t)b * NN + cz * (NN / RS)) * DH;
  f32x16 vmax;
  #pragma unroll
  for (int i = 0; i < 16; ++i) vmax[i] = -3.0e38f;

  const int sr = tid >> 1;
  const int sh = tid & 1;

  for (int stage = 0; stage < NN / RS / 128; ++stage) {
    __syncthreads();
    {
      const size_t g = kbase + (size_t)(stage * 128 + sr) * DH + sh * 32;
      const unsigned short* gh = Khi + g;
      const unsigned short* gl = Klo + g;
      #pragma unroll
      for (int c = 0; c < 4; ++c) {
        s16x8 hv = *(const s16x8*)(gh + c * 8);
        s16x8 lv = *(const s16x8*)(gl + c * 8);
        const int chn = (sh * 4 + c) ^ (sr & 7);
        *(s16x8*)&KHs[(sr * 8 + chn) * 8] = hv;
        *(s16x8*)&KLs[(sr * 8 + chn) * 8] = lv;
      }
    }
    __syncthreads();

    #pragma unroll
    for (int ksub = 0; ksub < 4; ++ksub) {
      const int kr = ksub * 32 + l31;
      f32x16 acc;
      #pragma unroll
      for (int i = 0; i < 16; ++i) acc[i] = 0.f;
      #pragma unroll
      for (int ks = 0; ks < 4; ++ks) {
        const int chn = (ks * 2 + hi5) ^ (kr & 7);
        s16x8 ah = *(const s16x8*)&KHs[(kr * 8 + chn) * 8];
        s16x8 al = *(const s16x8*)&KLs[(kr * 8 + chn) * 8];
        acc = __builtin_amdgcn_mfma_f32_32x32x16_bf16(ah, qh[ks], acc, 0, 0, 0);
        acc = __builtin_amdgcn_mfma_f32_32x32x16_bf16(al, qh[ks], acc, 0, 0, 0);
        acc = __builtin_amdgcn_mfma_f32_32x32x16_bf16(ah, ql[ks], acc, 0, 0, 0);
      }
      #pragma unroll
      for (int i = 0; i < 16; ++i) vmax[i] = fmaxf(vmax[i], acc[i]);
    }
  }

  float m = vmax[0];
  #pragma unroll
  for (int i = 1; i < 16; ++i) m = fmaxf(m, vmax[i]);
  m = fmaxf(m, __shfl_xor(m, 32));
  if (lane < 32)
    Mmax[((size_t)cz * NB + b) * NN + qbase + w * 32 + lane] = m;
}

// ---------------------------------------------------------------------------
// B0: keys + mean for all rows (parallel, 128 blocks)
// ---------------------------------------------------------------------------
__global__ __launch_bounds__(256) void mstat_kernel(const float* __restrict__ Q,
                                                    const float* __restrict__ Mmax,
                                                    const float* __restrict__ Kpart,
                                                    unsigned int* __restrict__ keysW,
                                                    float* __restrict__ meanv) {
  __shared__ float Ksl[64];
  const int b = blockIdx.y;
  const int seg = blockIdx.x;
  const int tid = threadIdx.x;
  if (tid < 64) {
    float s = 0.f;
    #pragma unroll
    for (int c = 0; c < 32; ++c) s += Kpart[((size_t)b * 32 + c) * 64 + tid];
    Ksl[tid] = s;
  }
  __syncthreads();
  const int i = seg * 256 + tid;
  float mv = -3.0e38f;
  #pragma unroll
  for (int cz = 0; cz < RS; ++cz)
    mv = fmaxf(mv, Mmax[((size_t)cz * NB + b) * NN + i]);
  const float* qrow = Q + ((size_t)b * NN + i) * DH;
  float s = 0.f;
  #pragma unroll
  for (int d4 = 0; d4 < 16; ++d4) {
    float4 qv = *(const float4*)(qrow + d4 * 4);
    s = fmaf(qv.x, Ksl[d4 * 4 + 0], s);
    s = fmaf(qv.y, Ksl[d4 * 4 + 1], s);
    s = fmaf(qv.z, Ksl[d4 * 4 + 2], s);
    s = fmaf(qv.w, Ksl[d4 * 4 + 3], s);
  }
  const float mean = s * (1.0f / NN);
  meanv[(size_t)b * NN + i] = mean;
  keysW[(size_t)b * NN + i] = enc(mv - mean);
}

// ---------------------------------------------------------------------------
// shared radix helper
// ---------------------------------------------------------------------------
static __device__ unsigned int radix_thresh(const unsigned int* kreg, int lane,
                                            int wid, int* red) {
  unsigned int v = 0u;
  for (int bit = 31; bit >= 0; --bit) {
    const unsigned int cand = v | (1u << bit);
    int c = 0;
    #pragma unroll
    for (int f = 0; f < 8; ++f) c += (kreg[f] >= cand) ? 1 : 0;
    #pragma unroll
    for (int off = 1; off < 64; off <<= 1) c += __shfl_xor(c, off);
    if (lane == 0) red[wid] = c;
    __syncthreads();
    if (red[0] + red[1] + red[2] + red[3] >= NSEL) v = cand;
    __syncthreads();
  }
  return v;
}

// ---------------------------------------------------------------------------
// B1: radix pass 1 + boundary-band collection
// ---------------------------------------------------------------------------
__global__ __launch_bounds__(256) void radix1_kernel(const unsigned int* __restrict__ keysW,
                                                     int* __restrict__ Band,
                                                     int* __restrict__ nband) {
  __shared__ int red[4];
  __shared__ int cntS;
  const int b = blockIdx.x;
  const int tid = threadIdx.x;
  const int lane = tid & 63, wid = tid >> 6;
  const int base = tid * 8;

  unsigned int kreg[8];
  #pragma unroll
  for (int f = 0; f < 8; ++f) kreg[f] = keysW[(size_t)b * NN + base + f];
  if (tid == 0) cntS = 0;
  __syncthreads();

  const unsigned int v1 = radix_thresh(kreg, lane, wid, red);
  const float vf = dec(v1);

  #pragma unroll
  for (int f = 0; f < 8; ++f) {
    if (fabsf(dec(kreg[f]) - vf) <= EPSBAND) {
      int p = atomicAdd(&cntS, 1);
      Band[(size_t)b * NN + p] = base + f;
    }
  }
  __syncthreads();
  if (tid == 0) nband[b] = cntS;
}

// ---------------------------------------------------------------------------
// B2: exact fp32 rowmax recheck for band rows
// ---------------------------------------------------------------------------
__global__ __launch_bounds__(256) void recheck_kernel(const float* __restrict__ Q,
                                                      const float* __restrict__ K,
                                                      const int* __restrict__ Band,
                                                      const int* __restrict__ nband,
                                                      const float* __restrict__ meanv,
                                                      unsigned int* __restrict__ keysW) {
  __shared__ float qsh[64];
  __shared__ float fred[4];
  const int b = blockIdx.y;
  const int nb_ = nband[b];
  const int tid = threadIdx.x;
  const int lane = tid & 63, wid = tid >> 6;

  for (int n = blockIdx.x; n < nb_; n += MAXB) {
    const int row = Band[(size_t)b * NN + n];
    __syncthreads();
    if (tid < 64) qsh[tid] = Q[((size_t)b * NN + row) * DH + tid];
    __syncthreads();
    float lmax = -3.0e38f;
    for (int j = tid; j < NN; j += 256) {
      const float* krow = K + ((size_t)b * NN + j) * DH;
      float s = 0.f;
      #pragma unroll
      for (int d4 = 0; d4 < 16; ++d4) {
        float4 kv = *(const float4*)(krow + d4 * 4);
        s = fmaf(kv.x, qsh[d4 * 4 + 0], s);
        s = fmaf(kv.y, qsh[d4 * 4 + 1], s);
        s = fmaf(kv.z, qsh[d4 * 4 + 2], s);
        s = fmaf(kv.w, qsh[d4 * 4 + 3], s);
      }
      lmax = fmaxf(lmax, s);
    }
    #pragma unroll
    for (int off = 1; off < 64; off <<= 1)
      lmax = fmaxf(lmax, __shfl_xor(lmax, off));
    if (lane == 0) fred[wid] = lmax;
    __syncthreads();
    if (tid == 0) {
      const float mx = fmaxf(fmaxf(fred[0], fred[1]), fmaxf(fred[2], fred[3]));
      keysW[(size_t)b * NN + row] = enc(mx - meanv[(size_t)b * NN + row]);
    }
  }
}

// ---------------------------------------------------------------------------
// B3: radix pass 2 + compaction. Also emits pos[b][i] = position in Isel
// (or -1), exactly one write per row (same thread owns a row in both passes).
// ---------------------------------------------------------------------------
__global__ __launch_bounds__(256) void radix2_kernel(const unsigned int* __restrict__ keysW,
                                                     int* __restrict__ Isel,
                                                     int* __restrict__ pos) {
  __shared__ int red[4];
  const int b = blockIdx.x;
  const int tid = threadIdx.x;
  const int lane = tid & 63, wid = tid >> 6;
  const int base = tid * 8;

  unsigned int kreg[8];
  #pragma unroll
  for (int f = 0; f < 8; ++f) kreg[f] = keysW[(size_t)b * NN + base + f];
  __syncthreads();

  const unsigned int v2 = radix_thresh(kreg, lane, wid, red);

  // pass 1: strictly greater
  int flg[8];
  int cnt = 0;
  #pragma unroll
  for (int f = 0; f < 8; ++f) { flg[f] = (kreg[f] > v2) ? 1 : 0; cnt += flg[f]; }
  int scan = cnt;
  #pragma unroll
  for (int off = 1; off < 64; off <<= 1) {
    const int t = __shfl_up(scan, off);
    if (lane >= off) scan += t;
  }
  if (lane == 63) red[wid] = scan;
  __syncthreads();
  int wbase = 0;
  for (int ww = 0; ww < wid; ++ww) wbase += red[ww];
  const int cg = red[0] + red[1] + red[2] + red[3];
  int p = wbase + scan - cnt;
  #pragma unroll
  for (int f = 0; f < 8; ++f) {
    if (flg[f]) {
      Isel[b * NSEL + p] = base + f;
      pos[(size_t)b * NN + base + f] = p;
      ++p;
    } else {
      pos[(size_t)b * NN + base + f] = -1;  // may be upgraded in pass 2
    }
  }
  __syncthreads();

  // pass 2: equal, lowest indices first
  const int need = NSEL - cg;
  cnt = 0;
  #pragma unroll
  for (int f = 0; f < 8; ++f) { flg[f] = (kreg[f] == v2) ? 1 : 0; cnt += flg[f]; }
  scan = cnt;
  #pragma unroll
  for (int off = 1; off < 64; off <<= 1) {
    const int t = __shfl_up(scan, off);
    if (lane >= off) scan += t;
  }
  if (lane == 63) red[wid] = scan;
  __syncthreads();
  wbase = 0;
  for (int ww = 0; ww < wid; ++ww) wbase += red[ww];
  p = wbase + scan - cnt;
  #pragma unroll
  for (int f = 0; f < 8; ++f) {
    if (flg[f]) {
      if (p < need) {
        Isel[b * NSEL + cg + p] = base + f;
        pos[(size_t)b * NN + base + f] = cg + p;
      }
      ++p;
    }
  }
}

// ---------------------------------------------------------------------------
// Kernel D (MFMA): flash partials via bf16x3 matrix cores. KS=4: each block
// covers a 512-key chunk; 4 waves x 128 keys. Conventions proven in round 9.
// ---------------------------------------------------------------------------
__global__ __launch_bounds__(256, 2) void attn_mfma(const float* __restrict__ Q,
                                                    const unsigned short* __restrict__ Khi,
                                                    const unsigned short* __restrict__ Klo,
                                                    const unsigned short* __restrict__ VThi,
                                                    const unsigned short* __restrict__ VTlo,
                                                    const int* __restrict__ Isel,
                                                    float* __restrict__ Pm,
                                                    float* __restrict__ Pl,
                                                    float* __restrict__ Po) {
  __shared__ float wmax[4][32];
  __shared__ float wl[4][32];
  __shared__ __align__(16) float Opart[4][32][68];  // pad 68: spread banks
  const int b = blockIdx.z, kc = blockIdx.y, g = blockIdx.x;
  const int tid = threadIdx.x, w = tid >> 6, lane = tid & 63;
  const int l31 = lane & 31, h = lane >> 5;

  // --- Q B-fragments (bf16 hi/lo split, on the fly) ---
  const int lq = g * 32 + l31;
  const int qidx = (lq < NSEL) ? Isel[b * NSEL + lq] : Isel[b * NSEL];
  s16x8 qbh[4], qbl[4];
  {
    const float* qr = Q + ((size_t)b * NN + qidx) * DH;
    #pragma unroll
    for (int s = 0; s < 4; ++s) {
      const int d0 = s * 16 + h * 8;
      float4 x = *(const float4*)(qr + d0);
      float4 y = *(const float4*)(qr + d0 + 4);
      float v[8] = {x.x, x.y, x.z, x.w, y.x, y.y, y.z, y.w};
      union { unsigned short u[8]; s16x8 s8; } H, L;
      #pragma unroll
      for (int j = 0; j < 8; ++j) {
        const unsigned short hh = f2bf(v[j]);
        H.u[j] = hh;
        L.u[j] = f2bf(v[j] - bf2f(hh));
      }
      qbh[s] = H.s8;
      qbl[s] = L.s8;
    }
  }

  // --- scores: 4 k-tiles of 32, bf16x3 ---
  const size_t krow0 = (size_t)b * NN + kc * CHUNK + w * 128;
  f32x16 p[4];
  #pragma unroll
  for (int t = 0; t < 4; ++t) {
    const unsigned short* kh = Khi + (krow0 + t * 32 + l31) * DH + h * 8;
    const unsigned short* kl = Klo + (krow0 + t * 32 + l31) * DH + h * 8;
    f32x16 acc;
    #pragma unroll
    for (int i = 0; i < 16; ++i) acc[i] = 0.f;
    #pragma unroll
    for (int s = 0; s < 4; ++s) {
      const s16x8 ah = *(const s16x8*)(kh + s * 16);
      const s16x8 al = *(const s16x8*)(kl + s * 16);
      acc = __builtin_amdgcn_mfma_f32_32x32x16_bf16(ah, qbh[s], acc, 0, 0, 0);
      acc = __builtin_amdgcn_mfma_f32_32x32x16_bf16(al, qbh[s], acc, 0, 0, 0);
      acc = __builtin_amdgcn_mfma_f32_32x32x16_bf16(ah, qbl[s], acc, 0, 0, 0);
    }
    p[t] = acc;
  }

  // --- chunk max per q (q = l31 is lane-local) ---
  float rmax = p[0][0];
  #pragma unroll
  for (int t = 0; t < 4; ++t)
    #pragma unroll
    for (int i = 0; i < 16; ++i) rmax = fmaxf(rmax, p[t][i]);
  rmax = fmaxf(rmax, __shfl_xor(rmax, 32));
  if (lane < 32) wmax[w][lane] = rmax;
  __syncthreads();
  const float gmax = fmaxf(fmaxf(wmax[0][l31], wmax[1][l31]),
                           fmaxf(wmax[2][l31], wmax[3][l31]));
  const float m = gmax * 0.125f;  // scaled max (1/sqrt(64))

  // --- P = exp(s*0.125 - m); partial l ---
  float lsum = 0.f;
  #pragma unroll
  for (int t = 0; t < 4; ++t)
    #pragma unroll
    for (int i = 0; i < 16; ++i) {
      const float e = __expf(fmaf(p[t][i], 0.125f, -m));
      p[t][i] = e;
      lsum += e;
    }
  lsum += __shfl_xor(lsum, 32);
  if (lane < 32) wl[w][lane] = lsum;

  // --- PV: per 16-k step build P^T B-frag (hi+lo) and MFMA with VT ---
  f32x16 oacc[2];
  #pragma unroll
  for (int i = 0; i < 16; ++i) { oacc[0][i] = 0.f; oacc[1][i] = 0.f; }

  #pragma unroll
  for (int s = 0; s < 8; ++s) {
    const int t = s >> 1, kb = s & 1;
    float pr[8];
    #pragma unroll
    for (int j = 0; j < 8; ++j) pr[j] = p[t][kb * 8 + j];
    unsigned int ah[4], al[4];
    #pragma unroll
    for (int pi = 0; pi < 4; ++pi) {
      const unsigned short h0 = f2bf(pr[pi * 2]);
      const unsigned short h1 = f2bf(pr[pi * 2 + 1]);
      ah[pi] = (unsigned int)h0 | ((unsigned int)h1 << 16);
      al[pi] = (unsigned int)f2bf(pr[pi * 2] - bf2f(h0)) |
               ((unsigned int)f2bf(pr[pi * 2 + 1] - bf2f(h1)) << 16);
    }
    unsigned int sh_[4], sl_[4];
    #pragma unroll
    for (int pi = 0; pi < 4; ++pi) {
      sh_[pi] = (unsigned int)__shfl_xor((int)ah[pi], 32);
      sl_[pi] = (unsigned int)__shfl_xor((int)al[pi], 32);
    }
    union { int4 i4; s16x8 s8; } BH, BL;
    if (h == 0) {
      BH.i4 = make_int4((int)ah[0], (int)ah[1], (int)sh_[0], (int)sh_[1]);
      BL.i4 = make_int4((int)al[0], (int)al[1], (int)sl_[0], (int)sl_[1]);
    } else {
      BH.i4 = make_int4((int)sh_[2], (int)sh_[3], (int)ah[2], (int)ah[3]);
      BL.i4 = make_int4((int)sl_[2], (int)sl_[3], (int)al[2], (int)al[3]);
    }
    const size_t koff = (size_t)kc * CHUNK + w * 128 + s * 16 + h * 8;
    #pragma unroll
    for (int dt = 0; dt < 2; ++dt) {
      const size_t vrow = ((size_t)b * DH + dt * 32 + l31) * NN + koff;
      const s16x8 av = *(const s16x8*)(VThi + vrow);
      const s16x8 avl = *(const s16x8*)(VTlo + vrow);
      oacc[dt] = __builtin_amdgcn_mfma_f32_32x32x16_bf16(av, BH.s8, oacc[dt], 0, 0, 0);
      oacc[dt] = __builtin_amdgcn_mfma_f32_32x32x16_bf16(av, BL.s8, oacc[dt], 0, 0, 0);
      oacc[dt] = __builtin_amdgcn_mfma_f32_32x32x16_bf16(avl, BH.s8, oacc[dt], 0, 0, 0);
    }
  }

  // --- write per-wave O partial: lane holds q=l31, d=(r&3)+8(r>>2)+4h+32dt ---
  #pragma unroll
  for (int dt = 0; dt < 2; ++dt)
    #pragma unroll
    for (int rg = 0; rg < 4; ++rg) {
      const int d0 = dt * 32 + rg * 8 + h * 4;
      float4 vv;
      vv.x = oacc[dt][rg * 4 + 0];
      vv.y = oacc[dt][rg * 4 + 1];
      vv.z = oacc[dt][rg * 4 + 2];
      vv.w = oacc[dt][rg * 4 + 3];
      *(float4*)&Opart[w][l31][d0] = vv;
    }
  __syncthreads();

  // --- cross-wave reduce + writeout ---
  const int q = tid >> 3, dg = (tid & 7) * 8;
  float4 s0, s1;
  s0.x = s0.y = s0.z = s0.w = 0.f;
  s1.x = s1.y = s1.z = s1.w = 0.f;
  #pragma unroll
  for (int ww = 0; ww < 4; ++ww) {
    const float4 a = *(const float4*)&Opart[ww][q][dg];
    const float4 c = *(const float4*)&Opart[ww][q][dg + 4];
    s0.x += a.x; s0.y += a.y; s0.z += a.z; s0.w += a.w;
    s1.x += c.x; s1.y += c.y; s1.z += c.z; s1.w += c.w;
  }
  const int lq2 = g * 32 + q;
  if (lq2 < NSEL) {
    const size_t row = ((size_t)b * NSEL + lq2) * KS + kc;
    *(float4*)(Po + row * 64 + dg) = s0;
    *(float4*)(Po + row * 64 + dg + 4) = s1;
    if (dg == 0) {
      const float gm2 = fmaxf(fmaxf(wmax[0][q], wmax[1][q]),
                              fmaxf(wmax[2][q], wmax[3][q]));
      Pm[row] = gm2 * 0.125f;
      Pl[row] = wl[0][q] + wl[1][q] + wl[2][q] + wl[3][q];
    }
  }
}

// ---------------------------------------------------------------------------
// Fused fill+combine: one wave per output row. pos[b][i] >= 0 -> merge the
// KS attention partials; else mean-of-V fill. Branch is wave-uniform.
// ---------------------------------------------------------------------------
__global__ __launch_bounds__(256) void fill_combine(const float* __restrict__ V,
                                                    const int* __restrict__ pos,
                                                    const float* __restrict__ Pm,
                                                    const float* __restrict__ Pl,
                                                    const float* __restrict__ Po,
                                                    float* __restrict__ out) {
  const size_t row = (size_t)blockIdx.x * 4 + (threadIdx.x >> 6);
  const int lane = threadIdx.x & 63;
  const int p = pos[row];
  if (p < 0) {
    float x = V[row * DH + lane];
    #pragma unroll
    for (int off = 1; off < 64; off <<= 1) x += __shfl_xor(x, off);
    out[row * DH + lane] = x * (1.0f / DH);
  } else {
    const int b = (int)(row / NN);
    const size_t base = ((size_t)b * NSEL + p) * KS;
    float pm[KS];
    float gm = -3.0e38f;
    #pragma unroll
    for (int c = 0; c < KS; ++c) { pm[c] = Pm[base + c]; gm = fmaxf(gm, pm[c]); }
    float L = 0.f, od = 0.f;
    #pragma unroll
    for (int c = 0; c < KS; ++c) {
      const float e = __expf(pm[c] - gm);
      L += Pl[base + c] * e;
      od += Po[(base + c) * 64 + lane] * e;
    }
    out[row * DH + lane] = od / L;
  }
}

// ---------------------------------------------------------------------------
extern "C" void kernel_launch(void* const* d_in, const int* in_sizes, int n_in,
                              void* d_out, int out_size, void* d_ws, size_t ws_size,
                              hipStream_t stream) {
  const float* Q = (const float*)d_in[0];
  const float* K = (const float*)d_in[1];
  const float* V = (const float*)d_in[2];
  // d_in[3] (seed) unused: U == n -> full permutation; max/mean are
  // permutation-invariant, so M equals rowmax - rowmean of the full QK^T.
  float* out = (float*)d_out;

  float* Mmax = (float*)d_ws;                                    // RS*NB*NN
  float* Kpart = Mmax + (size_t)RS * NB * NN;                    // NB*32*64
  unsigned int* keysW = (unsigned int*)(Kpart + (size_t)NB * 32 * 64);  // NB*NN
  float* meanv = (float*)(keysW + (size_t)NB * NN);              // NB*NN
  int* Band = (int*)(meanv + (size_t)NB * NN);                   // NB*NN
  int* nband = Band + (size_t)NB * NN;                           // NB (pad 16)
  int* Isel = nband + 16;                                        // NB*NSEL
  int* posA = Isel + NB * NSEL;                                  // NB*NN
  float* Pm = (float*)(posA + (size_t)NB * NN);                  // NB*NSEL*KS
  float* Pl = Pm + (size_t)NB * NSEL * KS;                       // NB*NSEL*KS
  float* Po = Pl + (size_t)NB * NSEL * KS;                       // NB*NSEL*KS*64
  unsigned short* Khi = (unsigned short*)(Po + (size_t)NB * NSEL * KS * 64);
  unsigned short* Klo = Khi + (size_t)NB * NN * DH;
  unsigned short* VThi = Klo + (size_t)NB * NN * DH;
  unsigned short* VTlo = VThi + (size_t)NB * NN * DH;

  conv_fused<<<dim3(NN / 64, NB, 2), 256, 0, stream>>>(K, V, Khi, Klo, VThi,
                                                       VTlo, Kpart);
  rowstat_mfma<<<dim3(NN / 128, NB, RS), 256, 0, stream>>>(Q, Khi, Klo, Mmax);
  mstat_kernel<<<dim3(8, NB), 256, 0, stream>>>(Q, Mmax, Kpart, keysW, meanv);
  radix1_kernel<<<dim3(NB), 256, 0, stream>>>(keysW, Band, nband);
  recheck_kernel<<<dim3(MAXB, NB), 256, 0, stream>>>(Q, K, Band, nband, meanv, keysW);
  radix2_kernel<<<dim3(NB), 256, 0, stream>>>(keysW, Isel, posA);
  attn_mfma<<<dim3(8, KS, NB), 256, 0, stream>>>(Q, Khi, Klo, VThi, VTlo, Isel,
                                                 Pm, Pl, Po);
  fill_combine<<<dim3(NB * NN / 4), 256, 0, stream>>>(V, posA, Pm, Pl, Po, out);
}

// Round 11
// 213.670 us; speedup vs baseline: 1.1630x; 1.0396x over previous
//
#include <hip/hip_runtime.h>

#define NB 16
#define NN 2048
#define DH 64
#define NSEL 228     // int(30 * ln(2048))
#define KS 4         // attention key-split chunks
#define CHUNK (NN / KS)
#define EPSBAND 2.0e-3f  // >> worst-case bf16x3 score error (~7e-4)

using s16x8 = __attribute__((ext_vector_type(8))) short;
using f32x16 = __attribute__((ext_vector_type(16))) float;

static __device__ __forceinline__ unsigned short f2bf(float x) {
  unsigned int u = __float_as_uint(x);
  u += 0x7fffu + ((u >> 16) & 1u);  // RNE; fine for finite data
  return (unsigned short)(u >> 16);
}
static __device__ __forceinline__ float bf2f(unsigned short h) {
  return __uint_as_float(((unsigned int)h) << 16);
}
static __device__ __forceinline__ unsigned int enc(float f) {
  unsigned int u = __float_as_uint(f);
  return (u & 0x80000000u) ? ~u : (u | 0x80000000u);
}
static __device__ __forceinline__ float dec(unsigned int k) {
  return (k & 0x80000000u) ? __uint_as_float(k & 0x7fffffffu)
                           : __uint_as_float(~k);
}

// ---------------------------------------------------------------------------
// Fused conversions (one kernel, z = mode):
//   mode 0: K 64-row chunk -> Khi/Klo (layout preserved) + partial colsums
//   mode 1: V 64-row chunk -> VThi/VTlo (transposed)
// ---------------------------------------------------------------------------
__global__ __launch_bounds__(256) void conv_fused(const float* __restrict__ K,
                                                  const float* __restrict__ V,
                                                  unsigned short* __restrict__ Khi,
                                                  unsigned short* __restrict__ Klo,
                                                  unsigned short* __restrict__ VThi,
                                                  unsigned short* __restrict__ VTlo,
                                                  float* __restrict__ Kpart) {
  __shared__ __align__(16) float T[64][65];
  const int b = blockIdx.y, ch = blockIdx.x;
  const int tid = threadIdx.x;
  const int r = tid >> 2;
  const int c0 = (tid & 3) * 16;

  if (blockIdx.z == 0) {
    const size_t off = ((size_t)b * NN + ch * 64 + r) * DH + c0;
    const float* src = K + off;
    float v[16];
    #pragma unroll
    for (int f = 0; f < 4; ++f) {
      float4 x = *(const float4*)(src + f * 4);
      v[f * 4 + 0] = x.x; v[f * 4 + 1] = x.y;
      v[f * 4 + 2] = x.z; v[f * 4 + 3] = x.w;
      T[r][c0 + f * 4 + 0] = x.x;
      T[r][c0 + f * 4 + 1] = x.y;
      T[r][c0 + f * 4 + 2] = x.z;
      T[r][c0 + f * 4 + 3] = x.w;
    }
    #pragma unroll
    for (int half = 0; half < 2; ++half) {
      union { unsigned short u[8]; s16x8 s; } H, L;
      #pragma unroll
      for (int j = 0; j < 8; ++j) {
        const float x = v[half * 8 + j];
        const unsigned short hh = f2bf(x);
        H.u[j] = hh;
        L.u[j] = f2bf(x - bf2f(hh));
      }
      *(s16x8*)(Khi + off + half * 8) = H.s;
      *(s16x8*)(Klo + off + half * 8) = L.s;
    }
    __syncthreads();
    if (tid < 64) {
      float s = 0.f;
      #pragma unroll 8
      for (int rr = 0; rr < 64; ++rr) s += T[rr][tid];
      Kpart[((size_t)b * 32 + ch) * 64 + tid] = s;
    }
  } else {
    const float* src = V + ((size_t)b * NN + ch * 64 + r) * DH + c0;
    #pragma unroll
    for (int f = 0; f < 4; ++f) {
      float4 x = *(const float4*)(src + f * 4);
      T[r][c0 + f * 4 + 0] = x.x;
      T[r][c0 + f * 4 + 1] = x.y;
      T[r][c0 + f * 4 + 2] = x.z;
      T[r][c0 + f * 4 + 3] = x.w;
    }
    __syncthreads();
    const int d = tid >> 2;
    const int j0 = (tid & 3) * 16;
    unsigned short* oh = VThi + ((size_t)b * DH + d) * NN + ch * 64 + j0;
    unsigned short* ol = VTlo + ((size_t)b * DH + d) * NN + ch * 64 + j0;
    #pragma unroll
    for (int half = 0; half < 2; ++half) {
      union { unsigned short u[8]; s16x8 s; } H, L;
      #pragma unroll
      for (int c = 0; c < 8; ++c) {
        const float x = T[j0 + half * 8 + c][d];
        const unsigned short hh = f2bf(x);
        H.u[c] = hh;
        L.u[c] = f2bf(x - bf2f(hh));
      }
      *(s16x8*)(oh + half * 8) = H.s;
      *(s16x8*)(ol + half * 8) = L.s;
    }
  }
}

// ---------------------------------------------------------------------------
// rowstat_keys (RS=1): one block owns 128 q-rows x ALL 2048 keys -> final
// rowmax in-register; fused key/mean computation (exact fp32 mean via
// q . Ksum; Q row re-read L2-hot). Eliminates mstat + Mmax roundtrip.
// MFMA body identical to the proven rowstat_mfma.
// ---------------------------------------------------------------------------
__global__ __launch_bounds__(256, 1) void rowstat_keys(const float* __restrict__ Q,
                                                       const unsigned short* __restrict__ Khi,
                                                       const unsigned short* __restrict__ Klo,
                                                       const float* __restrict__ Kpart,
                                                       unsigned int* __restrict__ keysW,
                                                       float* __restrict__ meanv) {
  __shared__ __align__(16) unsigned short KHs[128 * 64];
  __shared__ __align__(16) unsigned short KLs[128 * 64];
  __shared__ float Ksl[64];
  const int b = blockIdx.y;
  const int qbase = blockIdx.x * 128;
  const int tid = threadIdx.x;
  const int w = tid >> 6, lane = tid & 63;
  const int l31 = lane & 31, hi5 = lane >> 5;

  // full K column-sum (exact fp32, same summation order as old mstat)
  if (tid < 64) {
    float s = 0.f;
    #pragma unroll
    for (int c = 0; c < 32; ++c) s += Kpart[((size_t)b * 32 + c) * 64 + tid];
    Ksl[tid] = s;
  }

  s16x8 qh[4], ql[4];
  {
    const float* qrow = Q + ((size_t)b * NN + qbase + w * 32 + l31) * DH;
    #pragma unroll
    for (int ks = 0; ks < 4; ++ks) {
      const int d0 = ks * 16 + hi5 * 8;
      float4 x = *(const float4*)(qrow + d0);
      float4 y = *(const float4*)(qrow + d0 + 4);
      float v[8] = {x.x, x.y, x.z, x.w, y.x, y.y, y.z, y.w};
      union { unsigned short u[8]; s16x8 s; } H, L;
      #pragma unroll
      for (int j = 0; j < 8; ++j) {
        unsigned short h = f2bf(v[j]);
        H.u[j] = h;
        L.u[j] = f2bf(v[j] - bf2f(h));
      }
      qh[ks] = H.s;
      ql[ks] = L.s;
    }
  }

  const size_t kbase = (size_t)b * NN * DH;
  f32x16 vmax;
  #pragma unroll
  for (int i = 0; i < 16; ++i) vmax[i] = -3.0e38f;

  const int sr = tid >> 1;
  const int sh = tid & 1;

  for (int stage = 0; stage < NN / 128; ++stage) {
    __syncthreads();
    {
      const size_t g = kbase + (size_t)(stage * 128 + sr) * DH + sh * 32;
      const unsigned short* gh = Khi + g;
      const unsigned short* gl = Klo + g;
      #pragma unroll
      for (int c = 0; c < 4; ++c) {
        s16x8 hv = *(const s16x8*)(gh + c * 8);
        s16x8 lv = *(const s16x8*)(gl + c * 8);
        const int chn = (sh * 4 + c) ^ (sr & 7);
        *(s16x8*)&KHs[(sr * 8 + chn) * 8] = hv;
        *(s16x8*)&KLs[(sr * 8 + chn) * 8] = lv;
      }
    }
    __syncthreads();

    #pragma unroll
    for (int ksub = 0; ksub < 4; ++ksub) {
      const int kr = ksub * 32 + l31;
      f32x16 acc;
      #pragma unroll
      for (int i = 0; i < 16; ++i) acc[i] = 0.f;
      #pragma unroll
      for (int ks = 0; ks < 4; ++ks) {
        const int chn = (ks * 2 + hi5) ^ (kr & 7);
        s16x8 ah = *(const s16x8*)&KHs[(kr * 8 + chn) * 8];
        s16x8 al = *(const s16x8*)&KLs[(kr * 8 + chn) * 8];
        acc = __builtin_amdgcn_mfma_f32_32x32x16_bf16(ah, qh[ks], acc, 0, 0, 0);
        acc = __builtin_amdgcn_mfma_f32_32x32x16_bf16(al, qh[ks], acc, 0, 0, 0);
        acc = __builtin_amdgcn_mfma_f32_32x32x16_bf16(ah, ql[ks], acc, 0, 0, 0);
      }
      #pragma unroll
      for (int i = 0; i < 16; ++i) vmax[i] = fmaxf(vmax[i], acc[i]);
    }
  }

  float m = vmax[0];
  #pragma unroll
  for (int i = 1; i < 16; ++i) m = fmaxf(m, vmax[i]);
  m = fmaxf(m, __shfl_xor(m, 32));

  // fused key + mean (exact fp32: re-read Q row, dot with Ksl)
  if (lane < 32) {
    const int row = qbase + w * 32 + lane;
    const float* qr = Q + ((size_t)b * NN + row) * DH;
    float dot = 0.f;
    #pragma unroll
    for (int d4 = 0; d4 < 16; ++d4) {
      float4 qv = *(const float4*)(qr + d4 * 4);
      dot = fmaf(qv.x, Ksl[d4 * 4 + 0], dot);
      dot = fmaf(qv.y, Ksl[d4 * 4 + 1], dot);
      dot = fmaf(qv.z, Ksl[d4 * 4 + 2], dot);
      dot = fmaf(qv.w, Ksl[d4 * 4 + 3], dot);
    }
    const float mean = dot * (1.0f / NN);
    meanv[(size_t)b * NN + row] = mean;
    keysW[(size_t)b * NN + row] = enc(m - mean);
  }
}

// ---------------------------------------------------------------------------
// shared radix helper
// ---------------------------------------------------------------------------
static __device__ unsigned int radix_thresh(const unsigned int* kreg, int lane,
                                            int wid, int* red) {
  unsigned int v = 0u;
  for (int bit = 31; bit >= 0; --bit) {
    const unsigned int cand = v | (1u << bit);
    int c = 0;
    #pragma unroll
    for (int f = 0; f < 8; ++f) c += (kreg[f] >= cand) ? 1 : 0;
    #pragma unroll
    for (int off = 1; off < 64; off <<= 1) c += __shfl_xor(c, off);
    if (lane == 0) red[wid] = c;
    __syncthreads();
    if (red[0] + red[1] + red[2] + red[3] >= NSEL) v = cand;
    __syncthreads();
  }
  return v;
}

// ---------------------------------------------------------------------------
// select_fused: radix1 + boundary-band fp32 recheck + radix2 + compaction
// + posA, all in one per-batch block (keys in LDS). Band is typically 1-3
// rows; recheck reads L2-resident K.
// ---------------------------------------------------------------------------
__global__ __launch_bounds__(256) void select_fused(const float* __restrict__ Q,
                                                    const float* __restrict__ K,
                                                    const unsigned int* __restrict__ keysW,
                                                    const float* __restrict__ meanv,
                                                    int* __restrict__ Isel,
                                                    int* __restrict__ posA) {
  __shared__ unsigned int skeys[NN];
  __shared__ int blist[NN];
  __shared__ float qsh[64];
  __shared__ float fred[4];
  __shared__ int red[4];
  __shared__ int cntS;
  const int b = blockIdx.x;
  const int tid = threadIdx.x;
  const int lane = tid & 63, wid = tid >> 6;
  const int base = tid * 8;

  unsigned int kreg[8];
  #pragma unroll
  for (int f = 0; f < 8; ++f) {
    kreg[f] = keysW[(size_t)b * NN + base + f];
    skeys[base + f] = kreg[f];
  }
  if (tid == 0) cntS = 0;
  __syncthreads();

  // phase 1: approximate threshold + band collection
  const unsigned int v1 = radix_thresh(kreg, lane, wid, red);
  const float vf = dec(v1);
  #pragma unroll
  for (int f = 0; f < 8; ++f) {
    if (fabsf(dec(kreg[f]) - vf) <= EPSBAND) {
      int p = atomicAdd(&cntS, 1);
      blist[p] = base + f;
    }
  }
  __syncthreads();
  const int nb_ = cntS;

  // phase 2: exact fp32 rowmax recheck for band rows (serial over band,
  // block-parallel over keys; K[b] = 512 KB, L2-resident)
  for (int n = 0; n < nb_; ++n) {
    const int row = blist[n];
    __syncthreads();  // protect qsh reuse
    if (tid < 64) qsh[tid] = Q[((size_t)b * NN + row) * DH + tid];
    __syncthreads();
    float lmax = -3.0e38f;
    for (int j = tid; j < NN; j += 256) {
      const float* krow = K + ((size_t)b * NN + j) * DH;
      float s = 0.f;
      #pragma unroll
      for (int d4 = 0; d4 < 16; ++d4) {
        float4 kv = *(const float4*)(krow + d4 * 4);
        s = fmaf(kv.x, qsh[d4 * 4 + 0], s);
        s = fmaf(kv.y, qsh[d4 * 4 + 1], s);
        s = fmaf(kv.z, qsh[d4 * 4 + 2], s);
        s = fmaf(kv.w, qsh[d4 * 4 + 3], s);
      }
      lmax = fmaxf(lmax, s);
    }
    #pragma unroll
    for (int off = 1; off < 64; off <<= 1)
      lmax = fmaxf(lmax, __shfl_xor(lmax, off));
    if (lane == 0) fred[wid] = lmax;
    __syncthreads();
    if (tid == 0) {
      const float mx = fmaxf(fmaxf(fred[0], fred[1]), fmaxf(fred[2], fred[3]));
      skeys[row] = enc(mx - meanv[(size_t)b * NN + row]);
    }
  }
  __syncthreads();
  #pragma unroll
  for (int f = 0; f < 8; ++f) kreg[f] = skeys[base + f];

  // phase 3: exact threshold
  const unsigned int v2 = radix_thresh(kreg, lane, wid, red);

  // phase 4: compaction (strictly greater, then ==, index-ascending) + posA
  int flg[8];
  int cnt = 0;
  #pragma unroll
  for (int f = 0; f < 8; ++f) { flg[f] = (kreg[f] > v2) ? 1 : 0; cnt += flg[f]; }
  int scan = cnt;
  #pragma unroll
  for (int off = 1; off < 64; off <<= 1) {
    const int t = __shfl_up(scan, off);
    if (lane >= off) scan += t;
  }
  if (lane == 63) red[wid] = scan;
  __syncthreads();
  int wbase = 0;
  for (int ww = 0; ww < wid; ++ww) wbase += red[ww];
  const int cg = red[0] + red[1] + red[2] + red[3];
  int p = wbase + scan - cnt;
  #pragma unroll
  for (int f = 0; f < 8; ++f) {
    if (flg[f]) {
      Isel[b * NSEL + p] = base + f;
      posA[(size_t)b * NN + base + f] = p;
      ++p;
    } else {
      posA[(size_t)b * NN + base + f] = -1;  // may be upgraded in pass 2
    }
  }
  __syncthreads();

  const int need = NSEL - cg;
  cnt = 0;
  #pragma unroll
  for (int f = 0; f < 8; ++f) { flg[f] = (kreg[f] == v2) ? 1 : 0; cnt += flg[f]; }
  scan = cnt;
  #pragma unroll
  for (int off = 1; off < 64; off <<= 1) {
    const int t = __shfl_up(scan, off);
    if (lane >= off) scan += t;
  }
  if (lane == 63) red[wid] = scan;
  __syncthreads();
  wbase = 0;
  for (int ww = 0; ww < wid; ++ww) wbase += red[ww];
  p = wbase + scan - cnt;
  #pragma unroll
  for (int f = 0; f < 8; ++f) {
    if (flg[f]) {
      if (p < need) {
        Isel[b * NSEL + cg + p] = base + f;
        posA[(size_t)b * NN + base + f] = cg + p;
      }
      ++p;
    }
  }
}

// ---------------------------------------------------------------------------
// attn_mfma (proven round-9/10 kernel, KS=4): flash partials via bf16x3.
// ---------------------------------------------------------------------------
__global__ __launch_bounds__(256, 2) void attn_mfma(const float* __restrict__ Q,
                                                    const unsigned short* __restrict__ Khi,
                                                    const unsigned short* __restrict__ Klo,
                                                    const unsigned short* __restrict__ VThi,
                                                    const unsigned short* __restrict__ VTlo,
                                                    const int* __restrict__ Isel,
                                                    float* __restrict__ Pm,
                                                    float* __restrict__ Pl,
                                                    float* __restrict__ Po) {
  __shared__ float wmax[4][32];
  __shared__ float wl[4][32];
  __shared__ __align__(16) float Opart[4][32][68];
  const int b = blockIdx.z, kc = blockIdx.y, g = blockIdx.x;
  const int tid = threadIdx.x, w = tid >> 6, lane = tid & 63;
  const int l31 = lane & 31, h = lane >> 5;

  const int lq = g * 32 + l31;
  const int qidx = (lq < NSEL) ? Isel[b * NSEL + lq] : Isel[b * NSEL];
  s16x8 qbh[4], qbl[4];
  {
    const float* qr = Q + ((size_t)b * NN + qidx) * DH;
    #pragma unroll
    for (int s = 0; s < 4; ++s) {
      const int d0 = s * 16 + h * 8;
      float4 x = *(const float4*)(qr + d0);
      float4 y = *(const float4*)(qr + d0 + 4);
      float v[8] = {x.x, x.y, x.z, x.w, y.x, y.y, y.z, y.w};
      union { unsigned short u[8]; s16x8 s8; } H, L;
      #pragma unroll
      for (int j = 0; j < 8; ++j) {
        const unsigned short hh = f2bf(v[j]);
        H.u[j] = hh;
        L.u[j] = f2bf(v[j] - bf2f(hh));
      }
      qbh[s] = H.s8;
      qbl[s] = L.s8;
    }
  }

  const size_t krow0 = (size_t)b * NN + kc * CHUNK + w * 128;
  f32x16 p[4];
  #pragma unroll
  for (int t = 0; t < 4; ++t) {
    const unsigned short* kh = Khi + (krow0 + t * 32 + l31) * DH + h * 8;
    const unsigned short* kl = Klo + (krow0 + t * 32 + l31) * DH + h * 8;
    f32x16 acc;
    #pragma unroll
    for (int i = 0; i < 16; ++i) acc[i] = 0.f;
    #pragma unroll
    for (int s = 0; s < 4; ++s) {
      const s16x8 ah = *(const s16x8*)(kh + s * 16);
      const s16x8 al = *(const s16x8*)(kl + s * 16);
      acc = __builtin_amdgcn_mfma_f32_32x32x16_bf16(ah, qbh[s], acc, 0, 0, 0);
      acc = __builtin_amdgcn_mfma_f32_32x32x16_bf16(al, qbh[s], acc, 0, 0, 0);
      acc = __builtin_amdgcn_mfma_f32_32x32x16_bf16(ah, qbl[s], acc, 0, 0, 0);
    }
    p[t] = acc;
  }

  float rmax = p[0][0];
  #pragma unroll
  for (int t = 0; t < 4; ++t)
    #pragma unroll
    for (int i = 0; i < 16; ++i) rmax = fmaxf(rmax, p[t][i]);
  rmax = fmaxf(rmax, __shfl_xor(rmax, 32));
  if (lane < 32) wmax[w][lane] = rmax;
  __syncthreads();
  const float gmax = fmaxf(fmaxf(wmax[0][l31], wmax[1][l31]),
                           fmaxf(wmax[2][l31], wmax[3][l31]));
  const float m = gmax * 0.125f;

  float lsum = 0.f;
  #pragma unroll
  for (int t = 0; t < 4; ++t)
    #pragma unroll
    for (int i = 0; i < 16; ++i) {
      const float e = __expf(fmaf(p[t][i], 0.125f, -m));
      p[t][i] = e;
      lsum += e;
    }
  lsum += __shfl_xor(lsum, 32);
  if (lane < 32) wl[w][lane] = lsum;

  f32x16 oacc[2];
  #pragma unroll
  for (int i = 0; i < 16; ++i) { oacc[0][i] = 0.f; oacc[1][i] = 0.f; }

  #pragma unroll
  for (int s = 0; s < 8; ++s) {
    const int t = s >> 1, kb = s & 1;
    float pr[8];
    #pragma unroll
    for (int j = 0; j < 8; ++j) pr[j] = p[t][kb * 8 + j];
    unsigned int ah[4], al[4];
    #pragma unroll
    for (int pi = 0; pi < 4; ++pi) {
      const unsigned short h0 = f2bf(pr[pi * 2]);
      const unsigned short h1 = f2bf(pr[pi * 2 + 1]);
      ah[pi] = (unsigned int)h0 | ((unsigned int)h1 << 16);
      al[pi] = (unsigned int)f2bf(pr[pi * 2] - bf2f(h0)) |
               ((unsigned int)f2bf(pr[pi * 2 + 1] - bf2f(h1)) << 16);
    }
    unsigned int sh_[4], sl_[4];
    #pragma unroll
    for (int pi = 0; pi < 4; ++pi) {
      sh_[pi] = (unsigned int)__shfl_xor((int)ah[pi], 32);
      sl_[pi] = (unsigned int)__shfl_xor((int)al[pi], 32);
    }
    union { int4 i4; s16x8 s8; } BH, BL;
    if (h == 0) {
      BH.i4 = make_int4((int)ah[0], (int)ah[1], (int)sh_[0], (int)sh_[1]);
      BL.i4 = make_int4((int)al[0], (int)al[1], (int)sl_[0], (int)sl_[1]);
    } else {
      BH.i4 = make_int4((int)sh_[2], (int)sh_[3], (int)ah[2], (int)ah[3]);
      BL.i4 = make_int4((int)sl_[2], (int)sl_[3], (int)al[2], (int)al[3]);
    }
    const size_t koff = (size_t)kc * CHUNK + w * 128 + s * 16 + h * 8;
    #pragma unroll
    for (int dt = 0; dt < 2; ++dt) {
      const size_t vrow = ((size_t)b * DH + dt * 32 + l31) * NN + koff;
      const s16x8 av = *(const s16x8*)(VThi + vrow);
      const s16x8 avl = *(const s16x8*)(VTlo + vrow);
      oacc[dt] = __builtin_amdgcn_mfma_f32_32x32x16_bf16(av, BH.s8, oacc[dt], 0, 0, 0);
      oacc[dt] = __builtin_amdgcn_mfma_f32_32x32x16_bf16(av, BL.s8, oacc[dt], 0, 0, 0);
      oacc[dt] = __builtin_amdgcn_mfma_f32_32x32x16_bf16(avl, BH.s8, oacc[dt], 0, 0, 0);
    }
  }

  #pragma unroll
  for (int dt = 0; dt < 2; ++dt)
    #pragma unroll
    for (int rg = 0; rg < 4; ++rg) {
      const int d0 = dt * 32 + rg * 8 + h * 4;
      float4 vv;
      vv.x = oacc[dt][rg * 4 + 0];
      vv.y = oacc[dt][rg * 4 + 1];
      vv.z = oacc[dt][rg * 4 + 2];
      vv.w = oacc[dt][rg * 4 + 3];
      *(float4*)&Opart[w][l31][d0] = vv;
    }
  __syncthreads();

  const int q = tid >> 3, dg = (tid & 7) * 8;
  float4 s0, s1;
  s0.x = s0.y = s0.z = s0.w = 0.f;
  s1.x = s1.y = s1.z = s1.w = 0.f;
  #pragma unroll
  for (int ww = 0; ww < 4; ++ww) {
    const float4 a = *(const float4*)&Opart[ww][q][dg];
    const float4 c = *(const float4*)&Opart[ww][q][dg + 4];
    s0.x += a.x; s0.y += a.y; s0.z += a.z; s0.w += a.w;
    s1.x += c.x; s1.y += c.y; s1.z += c.z; s1.w += c.w;
  }
  const int lq2 = g * 32 + q;
  if (lq2 < NSEL) {
    const size_t row = ((size_t)b * NSEL + lq2) * KS + kc;
    *(float4*)(Po + row * 64 + dg) = s0;
    *(float4*)(Po + row * 64 + dg + 4) = s1;
    if (dg == 0) {
      const float gm2 = fmaxf(fmaxf(wmax[0][q], wmax[1][q]),
                              fmaxf(wmax[2][q], wmax[3][q]));
      Pm[row] = gm2 * 0.125f;
      Pl[row] = wl[0][q] + wl[1][q] + wl[2][q] + wl[3][q];
    }
  }
}

// ---------------------------------------------------------------------------
// Fused fill+combine: one wave per output row; wave-uniform branch.
// ---------------------------------------------------------------------------
__global__ __launch_bounds__(256) void fill_combine(const float* __restrict__ V,
                                                    const int* __restrict__ pos,
                                                    const float* __restrict__ Pm,
                                                    const float* __restrict__ Pl,
                                                    const float* __restrict__ Po,
                                                    float* __restrict__ out) {
  const size_t row = (size_t)blockIdx.x * 4 + (threadIdx.x >> 6);
  const int lane = threadIdx.x & 63;
  const int p = pos[row];
  if (p < 0) {
    float x = V[row * DH + lane];
    #pragma unroll
    for (int off = 1; off < 64; off <<= 1) x += __shfl_xor(x, off);
    out[row * DH + lane] = x * (1.0f / DH);
  } else {
    const int b = (int)(row / NN);
    const size_t base = ((size_t)b * NSEL + p) * KS;
    float pm[KS];
    float gm = -3.0e38f;
    #pragma unroll
    for (int c = 0; c < KS; ++c) { pm[c] = Pm[base + c]; gm = fmaxf(gm, pm[c]); }
    float L = 0.f, od = 0.f;
    #pragma unroll
    for (int c = 0; c < KS; ++c) {
      const float e = __expf(pm[c] - gm);
      L += Pl[base + c] * e;
      od += Po[(base + c) * 64 + lane] * e;
    }
    out[row * DH + lane] = od / L;
  }
}

// ---------------------------------------------------------------------------
extern "C" void kernel_launch(void* const* d_in, const int* in_sizes, int n_in,
                              void* d_out, int out_size, void* d_ws, size_t ws_size,
                              hipStream_t stream) {
  const float* Q = (const float*)d_in[0];
  const float* K = (const float*)d_in[1];
  const float* V = (const float*)d_in[2];
  // d_in[3] (seed) unused: U == n -> full permutation; max/mean are
  // permutation-invariant, so M equals rowmax - rowmean of the full QK^T.
  float* out = (float*)d_out;

  float* Kpart = (float*)d_ws;                                   // NB*32*64
  unsigned int* keysW = (unsigned int*)(Kpart + (size_t)NB * 32 * 64);  // NB*NN
  float* meanv = (float*)(keysW + (size_t)NB * NN);              // NB*NN
  int* Isel = (int*)(meanv + (size_t)NB * NN);                   // NB*NSEL
  int* posA = Isel + NB * NSEL;                                  // NB*NN
  float* Pm = (float*)(posA + (size_t)NB * NN);                  // NB*NSEL*KS
  float* Pl = Pm + (size_t)NB * NSEL * KS;                       // NB*NSEL*KS
  float* Po = Pl + (size_t)NB * NSEL * KS;                       // NB*NSEL*KS*64
  unsigned short* Khi = (unsigned short*)(Po + (size_t)NB * NSEL * KS * 64);
  unsigned short* Klo = Khi + (size_t)NB * NN * DH;
  unsigned short* VThi = Klo + (size_t)NB * NN * DH;
  unsigned short* VTlo = VThi + (size_t)NB * NN * DH;

  conv_fused<<<dim3(NN / 64, NB, 2), 256, 0, stream>>>(K, V, Khi, Klo, VThi,
                                                       VTlo, Kpart);
  rowstat_keys<<<dim3(NN / 128, NB), 256, 0, stream>>>(Q, Khi, Klo, Kpart,
                                                       keysW, meanv);
  select_fused<<<dim3(NB), 256, 0, stream>>>(Q, K, keysW, meanv, Isel, posA);
  attn_mfma<<<dim3(8, KS, NB), 256, 0, stream>>>(Q, Khi, Klo, VThi, VTlo, Isel,
                                                 Pm, Pl, Po);
  fill_combine<<<dim3(NB * NN / 4), 256, 0, stream>>>(V, posA, Pm, Pl, Po, out);
}